// Round 1
// 1159.139 us; speedup vs baseline: 1.0225x; 1.0225x over previous
//
#include <hip/hip_runtime.h>
#include <math.h>

// ---------------------------------------------------------------------------
// Temporal GNN. Round 8:
//  * tg_aggregate_h: 2 rows/wave, 32 lanes/row, 16B/lane dwordx4 gathers,
//    double-buffered col-index prefetch, predicated batched tail (padding
//    gathers hit the L1-hot own row). Attacks the latency/issue limit seen
//    in counters (VALUBusy 28%, occ 74%, no pipe saturated).
//  * tg_gemm: A-resident chunk order (stage A once per ka, double-pump
//    Bh/Bl) + 1-D grid with bijective chunked XCD swizzle so the two
//    col-tiles sharing an A strip co-reside on one XCD (A fetched once,
//    partner hits L2). Halves/quarters A HBM traffic; LDS/occupancy same.
//  Everything else unchanged from round 7 (fp16-split planes, 128x128 tile,
//  BK=64, global_load_lds, swizzled staging).
// ---------------------------------------------------------------------------

typedef __attribute__((ext_vector_type(8))) _Float16 half8;  // MFMA A/B frag
typedef __attribute__((ext_vector_type(4))) float floatx4;   // MFMA C/D
typedef __attribute__((ext_vector_type(8))) unsigned short us8; // 16B f16 vec

union HU { _Float16 h; unsigned short u; };

static __device__ __forceinline__ unsigned short f2h(float f) {
    HU x; x.h = (_Float16)f; return x.u;          // v_cvt_f16_f32 (RNE)
}
static __device__ __forceinline__ float h2f(unsigned short s) {
    HU x; x.u = s; return (float)x.h;
}

// async 16B/lane global -> LDS (dest = wave-uniform base + lane*16)
static __device__ __forceinline__ void gl_lds16(const void* g, void* l) {
    __builtin_amdgcn_global_load_lds(
        (const __attribute__((address_space(1))) unsigned int*)(g),
        (__attribute__((address_space(3))) unsigned int*)(l), 16, 0, 0);
}

// Split W[256][256] (k-major) into Bt'[n][768] = [Bh | Bl | Bh] f16 (transposed).
// grid (4,4,4): z = weight index. GCN GEMMs use only the first 512 columns.
__global__ void tg_splitB(const float* __restrict__ W0, const float* __restrict__ W1,
                          const float* __restrict__ W2, const float* __restrict__ W3,
                          unsigned short* __restrict__ B0, unsigned short* __restrict__ B1,
                          unsigned short* __restrict__ B2, unsigned short* __restrict__ B3)
{
    const float* Ws[4] = {W0, W1, W2, W3};
    unsigned short* Bs[4] = {B0, B1, B2, B3};
    const float* W = Ws[blockIdx.z];
    unsigned short* Bt = Bs[blockIdx.z];

    __shared__ float T[64][68];
    const int tk = blockIdx.x * 64, tn = blockIdx.y * 64;
    const int t = threadIdx.x;
#pragma unroll
    for (int j = 0; j < 4; ++j) {
        const int idx = t + 256 * j;
        const int k = idx >> 4, c4 = (idx & 15) * 4;
        const float4 v = *(const float4*)&W[(size_t)(tk + k) * 256 + tn + c4];
        T[k][c4] = v.x; T[k][c4 + 1] = v.y; T[k][c4 + 2] = v.z; T[k][c4 + 3] = v.w;
    }
    __syncthreads();
#pragma unroll
    for (int j = 0; j < 4; ++j) {
        const int idx = t + 256 * j;
        const int n = idx >> 4, q = (idx & 15) * 4;
        unsigned short hh[4], ll[4];
#pragma unroll
        for (int i = 0; i < 4; ++i) {
            const float f = T[q + i][n];
            hh[i] = f2h(f);
            ll[i] = f2h(f - h2f(hh[i]));
        }
        uint2 hp, lp;
        hp.x = (unsigned)hh[0] | ((unsigned)hh[1] << 16);
        hp.y = (unsigned)hh[2] | ((unsigned)hh[3] << 16);
        lp.x = (unsigned)ll[0] | ((unsigned)ll[1] << 16);
        lp.y = (unsigned)ll[2] | ((unsigned)ll[3] << 16);
        unsigned short* row = Bt + (size_t)(tn + n) * 768;
        *(uint2*)&row[tk + q]       = hp;   // Bh
        *(uint2*)&row[256 + tk + q] = lp;   // Bl
        *(uint2*)&row[512 + tk + q] = hp;   // Bh (pairs with Al, FT only)
    }
}

// Pre-split x[M][256] fp32 -> xh/xl f16 planes (zero pad rows >= N).
__global__ void tg_splitX(const float* __restrict__ x,
                          unsigned short* __restrict__ xh,
                          unsigned short* __restrict__ xl, int N, int Mpad)
{
    const int idx = blockIdx.x * 256 + threadIdx.x;
    const int r = idx >> 6, c4 = (idx & 63) * 4;
    if (r >= Mpad) return;
    ushort4 oh = {0, 0, 0, 0}, ol = {0, 0, 0, 0};
    if (r < N) {
        const float4 v = *(const float4*)&x[(size_t)r * 256 + c4];
        oh.x = f2h(v.x); ol.x = f2h(v.x - h2f(oh.x));
        oh.y = f2h(v.y); ol.y = f2h(v.y - h2f(oh.y));
        oh.z = f2h(v.z); ol.z = f2h(v.z - h2f(oh.z));
        oh.w = f2h(v.w); ol.w = f2h(v.w - h2f(oh.w));
    }
    *(ushort4*)&xh[(size_t)r * 256 + c4] = oh;
    *(ushort4*)&xl[(size_t)r * 256 + c4] = ol;
}

// m97-style GEMM, A-resident chunk schedule + XCD-paired col-tiles.
// 1-D grid of (Mpad/128)*2 blocks; logical id lg (after bijective chunked
// XCD swizzle) decodes to bx = lg>>1 (row tile), by = lg&1 (col tile), so
// the two blocks sharing an A strip land adjacently on the SAME XCD.
// Chunk schedules:
//   GCN (mode 1): for ka in {0,64,128,192}: [A(ka),Bh(ka)], [--,Bl(256+ka)]
//   FT  (mode 0): for ka: [Ah,Bh(ka)], [--,Bl(256+ka)], [Al,Bh(512+ka)]
// A staged only when it changes -> each A byte fetched once per block.
__global__ __launch_bounds__(256, 3)
void tg_gemm(const unsigned short* __restrict__ Ph,
             const unsigned short* __restrict__ Pl,
             const unsigned short* __restrict__ Bt,
             const float* __restrict__ bias, const float* __restrict__ rowscale,
             unsigned short* __restrict__ outHi, unsigned short* __restrict__ outLo,
             int M, int mode)
{
    __shared__ unsigned short sA[128 * 64], sB[128 * 64];  // 16 KB each

    const int t = threadIdx.x;
    const int w = t >> 6, lane = t & 63;
    const int quad = lane >> 4, l16 = lane & 15;
    const int wr = w >> 1, wc = w & 1;

    // bijective chunked XCD swizzle (m204 form): consecutive logical ids
    // within a chunk share an XCD -> (bx,0)/(bx,1) pairs co-resident.
    const int nwg = gridDim.x;
    const int swq = nwg >> 3, swr = nwg & 7;
    const int xcd = blockIdx.x & 7, oidx = blockIdx.x >> 3;
    const int lg = (xcd < swr ? xcd * (swq + 1)
                              : swr * (swq + 1) + (xcd - swr) * swq) + oidx;
    const int row0 = (lg >> 1) * 128;
    const int col0 = (lg & 1) * 128;

    floatx4 acc[4][4];
#pragma unroll
    for (int i = 0; i < 4; ++i)
#pragma unroll
        for (int j = 0; j < 4; ++j) acc[i][j] = (floatx4){0.f, 0.f, 0.f, 0.f};

    // staging decode: 8 lanes per row, slot (lane&7) holds source kg = slot^(row&7)
    const int srow = lane >> 3;
    const int kgx  = (lane & 7) ^ srow;
    const int rsw  = l16 & 7;

    auto chunk = [&](const unsigned short* __restrict__ Pa, int ka, int kb,
                     bool stA, bool first) {
        if (!first) __syncthreads();
#pragma unroll
        for (int i = 0; i < 4; ++i) {
            const int rr = w * 32 + i * 8;      // wave-uniform LDS row base
            if (stA)
                gl_lds16(Pa + (size_t)(row0 + rr + srow) * 256 + ka + kgx * 8, &sA[rr * 64]);
            gl_lds16(Bt + (size_t)(col0 + rr + srow) * 768 + kb + kgx * 8, &sB[rr * 64]);
        }
        __syncthreads();
#pragma unroll
        for (int ks = 0; ks < 2; ++ks) {
            const int kq = ks * 4 + quad;
            half8 af[4], bfr[4];
#pragma unroll
            for (int rt = 0; rt < 4; ++rt) {
                const int r = wr * 64 + rt * 16 + l16;
                af[rt] = *(const half8*)&sA[r * 64 + ((kq ^ rsw) * 8)];
            }
#pragma unroll
            for (int ct = 0; ct < 4; ++ct) {
                const int n = wc * 64 + ct * 16 + l16;
                bfr[ct] = *(const half8*)&sB[n * 64 + ((kq ^ rsw) * 8)];
            }
#pragma unroll
            for (int ct = 0; ct < 4; ++ct)
#pragma unroll
                for (int rt = 0; rt < 4; ++rt)
                    acc[rt][ct] = __builtin_amdgcn_mfma_f32_16x16x32_f16(
                        af[rt], bfr[ct], acc[rt][ct], 0, 0, 0);
        }
    };

    if (mode == 1) {
        for (int c = 0; c < 8; ++c) {
            const int ka = (c >> 1) << 6;
            chunk(Ph, ka, ((c & 1) << 8) + ka, !(c & 1), c == 0);
        }
    } else {
        int k4 = 0, ph = 0;
        for (int c = 0; c < 12; ++c) {
            const int ka = k4 << 6;
            chunk(ph == 2 ? Pl : Ph, ka, (ph << 8) + ka, ph != 1, c == 0);
            if (++ph == 3) { ph = 0; ++k4; }
        }
    }

    if (mode == 1) {   // GCN: f16(acc * rowscale)
#pragma unroll
        for (int rt = 0; rt < 4; ++rt) {
#pragma unroll
            for (int i = 0; i < 4; ++i) {
                const int gr = row0 + wr * 64 + rt * 16 + quad * 4 + i;
                const float s = rowscale[gr];
#pragma unroll
                for (int ct = 0; ct < 4; ++ct) {
                    const int gc = col0 + wc * 64 + ct * 16 + l16;
                    outHi[(size_t)gr * 256 + gc] = f2h(acc[rt][ct][i] * s);
                }
            }
        }
    } else {           // FT: relu(acc+bias) -> f16 hi/lo planes
#pragma unroll
        for (int rt = 0; rt < 4; ++rt) {
#pragma unroll
            for (int i = 0; i < 4; ++i) {
                const int gr = row0 + wr * 64 + rt * 16 + quad * 4 + i;
                if (gr >= M) continue;
#pragma unroll
                for (int ct = 0; ct < 4; ++ct) {
                    const int gc = col0 + wc * 64 + ct * 16 + l16;
                    float v = fmaxf(acc[rt][ct][i] + bias[gc], 0.f);
                    const unsigned short hi = f2h(v);
                    outHi[(size_t)gr * 256 + gc] = hi;
                    outLo[(size_t)gr * 256 + gc] = f2h(v - h2f(hi));
                }
            }
        }
    }
}

// LayerNorm + PE: reads f16 hi/lo pair, writes SINGLE f16 plane (into hh).
__global__ void tg_ln_pe(unsigned short* __restrict__ hh, const unsigned short* __restrict__ hl,
                         const float* __restrict__ g, const float* __restrict__ b, int N)
{
    const int gt = blockIdx.x * blockDim.x + threadIdx.x;
    const int row = gt >> 6;
    const int lane = threadIdx.x & 63;
    if (row >= N) return;
    const int c = lane * 4;
    unsigned short* hp = hh + (size_t)row * 256 + c;
    const ushort4 vh = *(const ushort4*)hp;
    const ushort4 vl = *(const ushort4*)(hl + (size_t)row * 256 + c);
    const float v0 = h2f(vh.x) + h2f(vl.x);
    const float v1 = h2f(vh.y) + h2f(vl.y);
    const float v2 = h2f(vh.z) + h2f(vl.z);
    const float v3 = h2f(vh.w) + h2f(vl.w);
    float s = v0 + v1 + v2 + v3;
#pragma unroll
    for (int m = 1; m < 64; m <<= 1) s += __shfl_xor(s, m, 64);
    const float mu = s * (1.f / 256.f);
    const float d0 = v0 - mu, d1 = v1 - mu, d2 = v2 - mu, d3 = v3 - mu;
    float q = d0 * d0 + d1 * d1 + d2 * d2 + d3 * d3;
#pragma unroll
    for (int m = 1; m < 64; m <<= 1) q += __shfl_xor(q, m, 64);
    const float rstd = 1.f / sqrtf(q * (1.f / 256.f) + 1e-5f);

    const float4 gg = *(const float4*)&g[c];
    const float4 bb = *(const float4*)&b[c];
    const float cexp = -0.035977892078031970f;  // -log(10000)/256
    const float fn = (float)row;
    const float div0 = expf((float)c * cexp);
    const float div1 = expf((float)(c + 2) * cexp);
    const float a0 = fn * div0;
    const float a1 = fn * div1;
    ushort4 o;
    o.x = f2h(d0 * rstd * gg.x + bb.x + sinf(a0));
    o.y = f2h(d1 * rstd * gg.y + bb.y + cosf(a0));
    o.z = f2h(d2 * rstd * gg.z + bb.z + sinf(a1));
    o.w = f2h(d3 * rstd * gg.w + bb.w + cosf(a1));
    *(ushort4*)hp = o;
}

__global__ void tg_count(const int* __restrict__ dst, int* __restrict__ deg, int E)
{
    const int e = blockIdx.x * blockDim.x + threadIdx.x;
    if (e < E) atomicAdd(&deg[dst[e]], 1);
}

__global__ void tg_dinv(const int* __restrict__ deg, float* __restrict__ dinv, int N)
{
    const int i = blockIdx.x * blockDim.x + threadIdx.x;
    if (i < N) dinv[i] = 1.f / sqrtf((float)(deg[i] + 1));  // +1 self-loop
}

__global__ void tg_scan1(const int* __restrict__ cnt, int* __restrict__ out,
                         int* __restrict__ sums, int N)
{
    __shared__ int tmp[1024];
    const int t = threadIdx.x;
    const int gid = blockIdx.x * 1024 + t;
    const int v = (gid < N) ? cnt[gid] : 0;
    tmp[t] = v;
    __syncthreads();
    for (int o = 1; o < 1024; o <<= 1) {
        const int add = (t >= o) ? tmp[t - o] : 0;
        __syncthreads();
        tmp[t] += add;
        __syncthreads();
    }
    if (gid < N) out[gid] = tmp[t] - v;
    if (t == 1023) sums[blockIdx.x] = tmp[t];
}

__global__ void tg_scan2(int* __restrict__ sums, int nb)
{
    __shared__ int tmp[1024];
    const int t = threadIdx.x;
    const int v = (t < nb) ? sums[t] : 0;
    tmp[t] = v;
    __syncthreads();
    for (int o = 1; o < 1024; o <<= 1) {
        const int add = (t >= o) ? tmp[t - o] : 0;
        __syncthreads();
        tmp[t] += add;
        __syncthreads();
    }
    if (t < nb) sums[t] = tmp[t] - v;
}

__global__ void tg_scan3(int* __restrict__ rowptr, const int* __restrict__ offs,
                         int N, int E)
{
    const int gid = blockIdx.x * 1024 + threadIdx.x;
    if (gid < N) rowptr[gid] += offs[gid >> 10];
    else if (gid == N) rowptr[N] = E;
}

__global__ void tg_fill(const int* __restrict__ src, const int* __restrict__ dst,
                        const int* __restrict__ rowptr, int* __restrict__ cursor,
                        int* __restrict__ col, int E)
{
    const int e = blockIdx.x * blockDim.x + threadIdx.x;
    if (e >= E) return;
    const int d = dst[e];
    const int p = atomicAdd(&cursor[d], 1);
    col[rowptr[d] + p] = src[e];
}

// out = relu(dinv[i]*(hwp[i] + sum hwp[src]) + bias): f16 in, single f16 out.
// 2 rows per wave, 32 lanes/row, 16B/lane dwordx4 gathers.
// Col indices double-buffered 8 ahead; tail is one predicated 8-wide batch
// (padding slots re-gather the own row: L1-hot, no extra L2 traffic).
__global__ void tg_aggregate_h(const unsigned short* __restrict__ hwpb,
                               const int* __restrict__ rowptr, const int* __restrict__ col,
                               const float* __restrict__ dinv, const float* __restrict__ bias,
                               unsigned short* __restrict__ hh, int N)
{
    const int gt = blockIdx.x * blockDim.x + threadIdx.x;
    const int row = gt >> 5;               // 32-thread group per row
    if (row >= N) return;
    const int hl = gt & 31;
    const int c = hl * 8;                  // 8 halves = 16 B per lane

    const unsigned short* base = hwpb + c;
    const int beg = rowptr[row], end = rowptr[row + 1];

    // own row (self-loop term)
    const us8 sv = *(const us8*)(base + (size_t)row * 256);
    float a[8];
#pragma unroll
    for (int j = 0; j < 8; ++j) a[j] = h2f(sv[j]);

    int p = beg;
    int rem = end - beg;
    int c0[8];
    if (rem >= 8) {
#pragma unroll
        for (int u = 0; u < 8; ++u) c0[u] = col[p + u];
    }
    while (rem >= 8) {
        int c1[8];
        const bool more = rem >= 16;
        if (more) {
#pragma unroll
            for (int u = 0; u < 8; ++u) c1[u] = col[p + 8 + u];
        }
        us8 v[8];
#pragma unroll
        for (int u = 0; u < 8; ++u)
            v[u] = *(const us8*)(base + (size_t)c0[u] * 256);
#pragma unroll
        for (int u = 0; u < 8; ++u)
#pragma unroll
            for (int j = 0; j < 8; ++j) a[j] += h2f(v[u][j]);
        if (more) {
#pragma unroll
            for (int u = 0; u < 8; ++u) c0[u] = c1[u];
        }
        p += 8; rem -= 8;
    }
    if (rem > 0) {
        const int last = end - 1;
        int ci[8];
#pragma unroll
        for (int u = 0; u < 8; ++u) {
            const int pp = (p + u < last) ? p + u : last;   // clamp: no OOB
            ci[u] = col[pp];
        }
        us8 v[8];
#pragma unroll
        for (int u = 0; u < 8; ++u)
            v[u] = *(const us8*)(base + (size_t)(u < rem ? ci[u] : row) * 256);
#pragma unroll
        for (int u = 0; u < 8; ++u) {
            if (u < rem) {
#pragma unroll
                for (int j = 0; j < 8; ++j) a[j] += h2f(v[u][j]);
            }
        }
    }

    const float di = dinv[row];
    const float4 b0 = *(const float4*)&bias[c];
    const float4 b1 = *(const float4*)&bias[c + 4];
    us8 o;
    o[0] = f2h(fmaxf(di * a[0] + b0.x, 0.f));
    o[1] = f2h(fmaxf(di * a[1] + b0.y, 0.f));
    o[2] = f2h(fmaxf(di * a[2] + b0.z, 0.f));
    o[3] = f2h(fmaxf(di * a[3] + b0.w, 0.f));
    o[4] = f2h(fmaxf(di * a[4] + b1.x, 0.f));
    o[5] = f2h(fmaxf(di * a[5] + b1.y, 0.f));
    o[6] = f2h(fmaxf(di * a[6] + b1.z, 0.f));
    o[7] = f2h(fmaxf(di * a[7] + b1.w, 0.f));
    *(us8*)&hh[(size_t)row * 256 + c] = o;
}

__global__ void tg_ranges(const int* __restrict__ batch, int* __restrict__ starts,
                          int N, int G)
{
    const int g = blockIdx.x * blockDim.x + threadIdx.x;
    if (g > G) return;
    int lo = 0, hi = N;
    while (lo < hi) {
        const int mid = (lo + hi) >> 1;
        if (batch[mid] < g) lo = mid + 1; else hi = mid;
    }
    starts[g] = lo;
}

// Mean-pool: block per graph, 4 waves split rows, lane owns 4 channels.
__global__ void tg_pool(const unsigned short* __restrict__ hh,
                        const int* __restrict__ starts, float* __restrict__ pooled, int G)
{
    __shared__ float sh[4][64][4];
    const int g = blockIdx.x;
    const int t = threadIdx.x;
    const int wv = t >> 6, lane = t & 63;
    const int c = lane * 4;
    const int beg = starts[g], end = starts[g + 1];
    float s0 = 0.f, s1 = 0.f, s2 = 0.f, s3 = 0.f;
    for (int r = beg + wv; r < end; r += 4) {
        const ushort4 vh = *(const ushort4*)&hh[(size_t)r * 256 + c];
        s0 += h2f(vh.x); s1 += h2f(vh.y); s2 += h2f(vh.z); s3 += h2f(vh.w);
    }
    sh[wv][lane][0] = s0; sh[wv][lane][1] = s1;
    sh[wv][lane][2] = s2; sh[wv][lane][3] = s3;
    __syncthreads();
    if (t < 64) {
        const float inv = 1.f / fmaxf((float)(end - beg), 1.f);
        float4 o;
        o.x = (sh[0][t][0] + sh[1][t][0] + sh[2][t][0] + sh[3][t][0]) * inv;
        o.y = (sh[0][t][1] + sh[1][t][1] + sh[2][t][1] + sh[3][t][1]) * inv;
        o.z = (sh[0][t][2] + sh[1][t][2] + sh[2][t][2] + sh[3][t][2]) * inv;
        o.w = (sh[0][t][3] + sh[1][t][3] + sh[2][t][3] + sh[3][t][3]) * inv;
        *(float4*)&pooled[(size_t)g * 256 + t * 4] = o;
    }
}

__global__ void tg_mlp(const float* __restrict__ A, const float* __restrict__ B,
                       const float* __restrict__ bias, float* __restrict__ Cout,
                       int M, int K, int Nc, int do_relu)
{
    const int idx = blockIdx.x * blockDim.x + threadIdx.x;
    if (idx >= M * Nc) return;
    const int m = idx / Nc;
    const int n = idx - m * Nc;
    float acc = 0.f;
    for (int k = 0; k < K; ++k) acc += A[(size_t)m * K + k] * B[(size_t)k * Nc + n];
    acc += bias[n];
    Cout[idx] = do_relu ? fmaxf(acc, 0.f) : acc;
}

extern "C" void kernel_launch(void* const* d_in, const int* in_sizes, int n_in,
                              void* d_out, int out_size, void* d_ws, size_t ws_size,
                              hipStream_t stream)
{
    const float* x    = (const float*)d_in[0];
    const float* W_ft = (const float*)d_in[1];
    const float* b_ft = (const float*)d_in[2];
    const float* ln_g = (const float*)d_in[3];
    const float* ln_b = (const float*)d_in[4];
    const float* W_g[3] = {(const float*)d_in[5], (const float*)d_in[7], (const float*)d_in[9]};
    const float* b_g[3] = {(const float*)d_in[6], (const float*)d_in[8], (const float*)d_in[10]};
    const float* W_c0 = (const float*)d_in[11];
    const float* b_c0 = (const float*)d_in[12];
    const float* W_c1 = (const float*)d_in[13];
    const float* b_c1 = (const float*)d_in[14];
    const float* W_c2 = (const float*)d_in[15];
    const float* b_c2 = (const float*)d_in[16];
    const int*   edge  = (const int*)d_in[17];
    const int*   batch = (const int*)d_in[18];

    const int N    = in_sizes[18];        // 100000
    const int E    = in_sizes[17] / 2;    // 1600000
    const int Mpad = (N + 127) & ~127;    // 100096
    const int H2   = in_sizes[14];        // 128
    const int Cc   = in_sizes[15] / H2;   // 4
    const int G    = out_size / Cc;       // 512

    const int* srcI = edge;
    const int* dstI = edge + E;

    size_t off = 0;
    auto alloc = [&](size_t bytes) {
        char* p = (char*)d_ws + off;
        off = (off + bytes + 255) & ~(size_t)255;
        return p;
    };
    unsigned short* hh   = (unsigned short*)alloc((size_t)Mpad * 256 * 2);
    unsigned short* hl   = (unsigned short*)alloc((size_t)Mpad * 256 * 2);
    unsigned short* hwpb = (unsigned short*)alloc((size_t)Mpad * 256 * 2); // aliases xh
    unsigned short* xl   = (unsigned short*)alloc((size_t)Mpad * 256 * 2);
    unsigned short* xh   = hwpb;  // x hi-plane lives in hwpb until FT GEMM done
    float* dinv   = (float*)alloc((size_t)Mpad * 4);
    int*   deg    = (int*)alloc((size_t)Mpad * 4);
    int*   rowptr = (int*)alloc((size_t)(N + 1) * 4);
    int*   cursor = (int*)alloc((size_t)N * 4);
    int*   col    = (int*)alloc((size_t)E * 4);
    int*   bsums  = (int*)alloc(1024 * 4);
    int*   starts = (int*)alloc((size_t)(G + 1) * 4);
    float* pooled = (float*)alloc((size_t)G * 256 * 4);
    float* z0     = (float*)alloc((size_t)G * 256 * 4);
    float* z1     = (float*)alloc((size_t)G * H2 * 4);
    unsigned short* Bt[4];
    for (int i = 0; i < 4; ++i)
        Bt[i] = (unsigned short*)alloc((size_t)256 * 768 * 2);
    (void)ws_size; (void)n_in;

    hipMemsetAsync(deg, 0, (size_t)Mpad * 4, stream);
    hipMemsetAsync(cursor, 0, (size_t)N * 4, stream);
    // zero pad rows of h planes (read by GCN GEMM A staging)
    hipMemsetAsync(hh + (size_t)N * 256, 0, (size_t)(Mpad - N) * 256 * 2, stream);
    hipMemsetAsync(hl + (size_t)N * 256, 0, (size_t)(Mpad - N) * 256 * 2, stream);

    // 0. weight prep + x split
    tg_splitB<<<dim3(4, 4, 4), dim3(256), 0, stream>>>(
        W_ft, W_g[0], W_g[1], W_g[2], Bt[0], Bt[1], Bt[2], Bt[3]);
    tg_splitX<<<dim3(Mpad / 4), dim3(256), 0, stream>>>(x, xh, xl, N, Mpad);

    const int nbx = (Mpad / 128) * 2;     // 1-D grid: lg>>1 = row tile, lg&1 = col tile
    // 1. feature transform -> h f16 hi/lo pair (K'=768: Ah.Bh + Ah.Bl + Al.Bh)
    tg_gemm<<<dim3(nbx), dim3(256), 0, stream>>>(xh, xl, Bt[0], b_ft, nullptr, hh, hl, N, 0);
    // 2. LayerNorm + PE: pair -> single f16 plane (in hh)
    tg_ln_pe<<<dim3((N + 3) / 4), dim3(256), 0, stream>>>(hh, hl, ln_g, ln_b, N);
    // 3. degrees + CSR build (rows = dst, cols = src)
    tg_count<<<dim3((E + 255) / 256), dim3(256), 0, stream>>>(dstI, deg, E);
    tg_dinv<<<dim3((Mpad + 255) / 256), dim3(256), 0, stream>>>(deg, dinv, Mpad);
    const int NB = (N + 1023) / 1024;
    tg_scan1<<<dim3(NB), dim3(1024), 0, stream>>>(deg, rowptr, bsums, N);
    tg_scan2<<<dim3(1), dim3(1024), 0, stream>>>(bsums, NB);
    tg_scan3<<<dim3((N + 1024) / 1024), dim3(1024), 0, stream>>>(rowptr, bsums, N, E);
    tg_fill<<<dim3((E + 255) / 256), dim3(256), 0, stream>>>(srcI, dstI, rowptr, cursor, col, E);
    // 4. GCN layers: hwpb = f16((h@W)*dinv) with K'=512 single-plane A;
    //    h = relu(dinv*(hwp[i]+sum hwp[src]) + b) single f16 plane
    for (int l = 0; l < 3; ++l) {
        tg_gemm<<<dim3(nbx), dim3(256), 0, stream>>>(hh, hh, Bt[l + 1], nullptr, dinv,
                                                     hwpb, nullptr, Mpad, 1);
        tg_aggregate_h<<<dim3((N + 7) / 8), dim3(256), 0, stream>>>(hwpb, rowptr, col, dinv,
                                                                    b_g[l], hh, N);
    }
    // 5. per-graph mean pool
    tg_ranges<<<dim3((G + 256) / 256), dim3(256), 0, stream>>>(batch, starts, N, G);
    tg_pool<<<dim3(G), dim3(256), 0, stream>>>(hh, starts, pooled, G);
    // 6. classifier MLP
    tg_mlp<<<dim3((G * 256 + 255) / 256), dim3(256), 0, stream>>>(pooled, W_c0, b_c0, z0, G, 256, 256, 1);
    tg_mlp<<<dim3((G * H2 + 255) / 256), dim3(256), 0, stream>>>(z0, W_c1, b_c1, z1, G, 256, H2, 1);
    tg_mlp<<<dim3((G * Cc + 255) / 256), dim3(256), 0, stream>>>(z1, W_c2, b_c2, (float*)d_out, G, H2, Cc, 0);
}

// Round 2
// 1091.132 us; speedup vs baseline: 1.0862x; 1.0623x over previous
//
#include <hip/hip_runtime.h>
#include <math.h>

// ---------------------------------------------------------------------------
// Temporal GNN. Round 9:
//  * NEW tg_ft_ln: fused feature-transform GEMM (f32 x read directly,
//    register hi/lo f16 split, K'=768 via Ah.Bh + Al.Bh + Ah.Bl) +
//    bias/ReLU + LayerNorm (f32 accumulators, cross-wave LDS stats) +
//    positional encoding, writing the single f16 h plane. Removes
//    tg_splitX, tg_ln_pe, the hl plane, and ~360MB of traffic.
//  * CSR build: count pass records perm[e]; fill pass is atomic-free.
//  * Bt shrunk to stride 512 (Bh|Bl), third copy dropped.
//  * tg_aggregate_h left as round 8: measured fabric-concurrency-bound at
//    3.85 TB/s with irreducible bytes (two different issue structures gave
//    identical BW/FETCH) -> at structural floor ~107us, no further edits.
//  * GCN GEMM unchanged (A-resident schedule, XCD-paired col tiles).
// ---------------------------------------------------------------------------

typedef __attribute__((ext_vector_type(8))) _Float16 half8;  // MFMA A/B frag
typedef __attribute__((ext_vector_type(4))) float floatx4;   // MFMA C/D
typedef __attribute__((ext_vector_type(8))) unsigned short us8; // 16B f16 vec

union HU { _Float16 h; unsigned short u; };

static __device__ __forceinline__ unsigned short f2h(float f) {
    HU x; x.h = (_Float16)f; return x.u;          // v_cvt_f16_f32 (RNE)
}
static __device__ __forceinline__ float h2f(unsigned short s) {
    HU x; x.u = s; return (float)x.h;
}

// async 16B/lane global -> LDS (dest = wave-uniform base + lane*16)
static __device__ __forceinline__ void gl_lds16(const void* g, void* l) {
    __builtin_amdgcn_global_load_lds(
        (const __attribute__((address_space(1))) unsigned int*)(g),
        (__attribute__((address_space(3))) unsigned int*)(l), 16, 0, 0);
}

// Split W[256][256] (k-major) into Bt'[n][512] = [Bh | Bl] f16 (transposed).
// grid (4,4,4): z = weight index.
__global__ void tg_splitB(const float* __restrict__ W0, const float* __restrict__ W1,
                          const float* __restrict__ W2, const float* __restrict__ W3,
                          unsigned short* __restrict__ B0, unsigned short* __restrict__ B1,
                          unsigned short* __restrict__ B2, unsigned short* __restrict__ B3)
{
    const float* Ws[4] = {W0, W1, W2, W3};
    unsigned short* Bs[4] = {B0, B1, B2, B3};
    const float* W = Ws[blockIdx.z];
    unsigned short* Bt = Bs[blockIdx.z];

    __shared__ float T[64][68];
    const int tk = blockIdx.x * 64, tn = blockIdx.y * 64;
    const int t = threadIdx.x;
#pragma unroll
    for (int j = 0; j < 4; ++j) {
        const int idx = t + 256 * j;
        const int k = idx >> 4, c4 = (idx & 15) * 4;
        const float4 v = *(const float4*)&W[(size_t)(tk + k) * 256 + tn + c4];
        T[k][c4] = v.x; T[k][c4 + 1] = v.y; T[k][c4 + 2] = v.z; T[k][c4 + 3] = v.w;
    }
    __syncthreads();
#pragma unroll
    for (int j = 0; j < 4; ++j) {
        const int idx = t + 256 * j;
        const int n = idx >> 4, q = (idx & 15) * 4;
        unsigned short hh[4], ll[4];
#pragma unroll
        for (int i = 0; i < 4; ++i) {
            const float f = T[q + i][n];
            hh[i] = f2h(f);
            ll[i] = f2h(f - h2f(hh[i]));
        }
        uint2 hp, lp;
        hp.x = (unsigned)hh[0] | ((unsigned)hh[1] << 16);
        hp.y = (unsigned)hh[2] | ((unsigned)hh[3] << 16);
        lp.x = (unsigned)ll[0] | ((unsigned)ll[1] << 16);
        lp.y = (unsigned)ll[2] | ((unsigned)ll[3] << 16);
        unsigned short* row = Bt + (size_t)(tn + n) * 512;
        *(uint2*)&row[tk + q]       = hp;   // Bh
        *(uint2*)&row[256 + tk + q] = lp;   // Bl
    }
}

// ---------------------------------------------------------------------------
// Fused FT GEMM + LayerNorm + PE. Tile 128 rows x 256 cols, 4 waves (2x2),
// wave tile 64x128, acc[4][8]. Per ka chunk (K=64):
//   stage {A: f32 x -> hi/lo f16 regs -> swizzled ds_write; sB = Bh}
//   P0/P1: acc += Ah.Bh + Al.Bh
//   stage sB = Bl ; P2: acc += Ah.Bl
// Epilogue: v = relu(acc + b_ft); per-row stats via 16-lane shfl + LDS;
// then per-rt stripes: dump acc -> LDS f32, rolled pass applies LN + PE
// (sin(ang + (col&1)*pi/2), libm sinf for large-arg accuracy), writes f16 h.
// ---------------------------------------------------------------------------
__global__ __launch_bounds__(256, 2)
void tg_ft_ln(const float* __restrict__ x, const unsigned short* __restrict__ Bt,
              const float* __restrict__ bias, const float* __restrict__ lng,
              const float* __restrict__ lnb, unsigned short* __restrict__ hh, int N)
{
    __shared__ unsigned short sAh[128 * 64];   // 16 KB
    __shared__ unsigned short sAl[128 * 64];   // 16 KB
    __shared__ unsigned short sB[256 * 64];    // 32 KB (Bh then Bl; then f32 scratch)
    __shared__ float sStats[128][2][2];        // [row][wc][{sum,sumsq}] 2 KB

    const int t = threadIdx.x;
    const int w = t >> 6, lane = t & 63;
    const int quad = lane >> 4, l16 = lane & 15;
    const int wr = w >> 1, wc = w & 1;
    const int row0 = blockIdx.x * 128;

    floatx4 acc[4][8];
#pragma unroll
    for (int i = 0; i < 4; ++i)
#pragma unroll
        for (int j = 0; j < 8; ++j) acc[i][j] = (floatx4){0.f, 0.f, 0.f, 0.f};

    // A staging map: thread -> (row, half); 4 slots (k-groups of 8) each
    const int arow = t >> 1;
    const int ahalf = t & 1;
    // B staging map (gl_lds16): 8 lanes/row, slot (lane&7) holds kg = slot^(row&7)
    const int srow = lane >> 3;
    const int kgx  = (lane & 7) ^ srow;
    const int rsw  = l16 & 7;

    for (int k4 = 0; k4 < 4; ++k4) {
        const int ka = k4 * 64;
        if (k4) __syncthreads();
        // --- stage A: read f32 x, split to hi/lo f16, swizzled ds_write ---
        {
            const int grow = row0 + arow;
            const bool ok = grow < N;
            const float* xp = x + (size_t)grow * 256 + ka + ahalf * 32;
#pragma unroll
            for (int j = 0; j < 4; ++j) {
                const int kg = ahalf * 4 + j;
                float4 v0 = {0.f, 0.f, 0.f, 0.f}, v1 = {0.f, 0.f, 0.f, 0.f};
                if (ok) {
                    v0 = *(const float4*)(xp + j * 8);
                    v1 = *(const float4*)(xp + j * 8 + 4);
                }
                const float f[8] = {v0.x, v0.y, v0.z, v0.w, v1.x, v1.y, v1.z, v1.w};
                us8 hi, lo;
#pragma unroll
                for (int i = 0; i < 8; ++i) {
                    hi[i] = f2h(f[i]);
                    lo[i] = f2h(f[i] - h2f(hi[i]));
                }
                const int ad = arow * 64 + ((kg ^ (arow & 7)) << 3);
                *(us8*)&sAh[ad] = hi;
                *(us8*)&sAl[ad] = lo;
            }
        }
        // --- stage sB = Bh(ka): 256 rows, 8 gl_lds16 per wave ---
#pragma unroll
        for (int i = 0; i < 8; ++i) {
            const int rr = w * 64 + i * 8;
            gl_lds16(Bt + (size_t)(rr + srow) * 512 + ka + kgx * 8, &sB[rr * 64]);
        }
        __syncthreads();
        // --- P0 + P1: Ah.Bh + Al.Bh ---
#pragma unroll
        for (int ks = 0; ks < 2; ++ks) {
            const int kq = ks * 4 + quad;
            half8 afh[4], afl[4];
#pragma unroll
            for (int rt = 0; rt < 4; ++rt) {
                const int r = wr * 64 + rt * 16 + l16;
                const int off = r * 64 + ((kq ^ rsw) << 3);
                afh[rt] = *(const half8*)&sAh[off];
                afl[rt] = *(const half8*)&sAl[off];
            }
#pragma unroll
            for (int cb = 0; cb < 2; ++cb) {
                half8 bfr[4];
#pragma unroll
                for (int c4 = 0; c4 < 4; ++c4) {
                    const int n = wc * 128 + (cb * 4 + c4) * 16 + l16;
                    bfr[c4] = *(const half8*)&sB[n * 64 + ((kq ^ rsw) << 3)];
                }
#pragma unroll
                for (int c4 = 0; c4 < 4; ++c4)
#pragma unroll
                    for (int rt = 0; rt < 4; ++rt) {
                        acc[rt][cb * 4 + c4] = __builtin_amdgcn_mfma_f32_16x16x32_f16(
                            afh[rt], bfr[c4], acc[rt][cb * 4 + c4], 0, 0, 0);
                        acc[rt][cb * 4 + c4] = __builtin_amdgcn_mfma_f32_16x16x32_f16(
                            afl[rt], bfr[c4], acc[rt][cb * 4 + c4], 0, 0, 0);
                    }
            }
        }
        __syncthreads();
        // --- stage sB = Bl(ka) ---
#pragma unroll
        for (int i = 0; i < 8; ++i) {
            const int rr = w * 64 + i * 8;
            gl_lds16(Bt + (size_t)(rr + srow) * 512 + 256 + ka + kgx * 8, &sB[rr * 64]);
        }
        __syncthreads();
        // --- P2: Ah.Bl ---
#pragma unroll
        for (int ks = 0; ks < 2; ++ks) {
            const int kq = ks * 4 + quad;
            half8 afh[4];
#pragma unroll
            for (int rt = 0; rt < 4; ++rt) {
                const int r = wr * 64 + rt * 16 + l16;
                afh[rt] = *(const half8*)&sAh[r * 64 + ((kq ^ rsw) << 3)];
            }
#pragma unroll
            for (int cb = 0; cb < 2; ++cb) {
                half8 bfr[4];
#pragma unroll
                for (int c4 = 0; c4 < 4; ++c4) {
                    const int n = wc * 128 + (cb * 4 + c4) * 16 + l16;
                    bfr[c4] = *(const half8*)&sB[n * 64 + ((kq ^ rsw) << 3)];
                }
#pragma unroll
                for (int c4 = 0; c4 < 4; ++c4)
#pragma unroll
                    for (int rt = 0; rt < 4; ++rt)
                        acc[rt][cb * 4 + c4] = __builtin_amdgcn_mfma_f32_16x16x32_f16(
                            afh[rt], bfr[c4], acc[rt][cb * 4 + c4], 0, 0, 0);
            }
        }
    }

    // --- stats: v = relu(acc + bias), per-row sum/sumsq over this wave's 128 cols
    float bs[8];
#pragma unroll
    for (int ct = 0; ct < 8; ++ct) bs[ct] = bias[wc * 128 + ct * 16 + l16];
#pragma unroll
    for (int rt = 0; rt < 4; ++rt) {
#pragma unroll
        for (int i = 0; i < 4; ++i) {
            float s = 0.f, q = 0.f;
#pragma unroll
            for (int ct = 0; ct < 8; ++ct) {
                const float v = fmaxf(acc[rt][ct][i] + bs[ct], 0.f);
                s += v; q += v * v;
            }
#pragma unroll
            for (int m = 1; m < 16; m <<= 1) {
                s += __shfl_xor(s, m, 64);
                q += __shfl_xor(q, m, 64);
            }
            if (l16 == 0) {
                const int rl = wr * 64 + rt * 16 + quad * 4 + i;
                sStats[rl][wc][0] = s;
                sStats[rl][wc][1] = q;
            }
        }
    }
    __syncthreads();   // stats ready; also all MFMA sB reads done -> sB reusable

    // --- per-rt stripes: dump acc (f32) to LDS, rolled LN+PE pass ---
    float* sC = (float*)sB;                      // 32 rows x 256 cols f32
    const float bias_c = bias[t];
    const float g_c = lng[t];
    const float b_c = lnb[t];
    const float cexp = -0.035977892078031970f;   // -log(10000)/256
    const float dv_c = expf((float)(t & ~1) * cexp);
    const float phase = (t & 1) ? 1.5707963267948966f : 0.f;

#pragma unroll
    for (int rt = 0; rt < 4; ++rt) {
#pragma unroll
        for (int i = 0; i < 4; ++i) {
            const int srl = wr * 16 + quad * 4 + i;     // stripe row 0..31
#pragma unroll
            for (int ct = 0; ct < 8; ++ct)
                sC[srl * 256 + wc * 128 + ct * 16 + l16] = acc[rt][ct][i];
        }
        __syncthreads();
        for (int q = 0; q < 32; ++q) {
            const int rl = (q >> 4) * 64 + rt * 16 + (q & 15);   // stats row 0..127
            const int gr = row0 + rl;
            if (gr < N) {
                const float sum = sStats[rl][0][0] + sStats[rl][1][0];
                const float sq  = sStats[rl][0][1] + sStats[rl][1][1];
                const float mu  = sum * (1.f / 256.f);
                const float var = sq * (1.f / 256.f) - mu * mu;
                const float rstd = 1.f / sqrtf(var + 1e-5f);
                const float v = fmaxf(sC[q * 256 + t] + bias_c, 0.f);
                const float nrm = (v - mu) * rstd * g_c + b_c;
                const float pe = sinf((float)gr * dv_c + phase);
                hh[(size_t)gr * 256 + t] = f2h(nrm + pe);
            }
        }
        __syncthreads();
    }
}

// GCN GEMM (round-8 structure): A-resident chunk order, XCD-paired col tiles.
// hwp = f16((h@W) * dinv_row), K'=512 = Bh|Bl against single-plane A.
__global__ __launch_bounds__(256, 3)
void tg_gemm(const unsigned short* __restrict__ Ph,
             const unsigned short* __restrict__ Bt,
             const float* __restrict__ rowscale,
             unsigned short* __restrict__ out)
{
    __shared__ unsigned short sA[128 * 64], sB[128 * 64];  // 16 KB each

    const int t = threadIdx.x;
    const int w = t >> 6, lane = t & 63;
    const int quad = lane >> 4, l16 = lane & 15;
    const int wr = w >> 1, wc = w & 1;

    // bijective chunked XCD swizzle: (bx,0)/(bx,1) pairs co-resident on one XCD
    const int nwg = gridDim.x;
    const int swq = nwg >> 3, swr = nwg & 7;
    const int xcd = blockIdx.x & 7, oidx = blockIdx.x >> 3;
    const int lg = (xcd < swr ? xcd * (swq + 1)
                              : swr * (swq + 1) + (xcd - swr) * swq) + oidx;
    const int row0 = (lg >> 1) * 128;
    const int col0 = (lg & 1) * 128;

    floatx4 acc[4][4];
#pragma unroll
    for (int i = 0; i < 4; ++i)
#pragma unroll
        for (int j = 0; j < 4; ++j) acc[i][j] = (floatx4){0.f, 0.f, 0.f, 0.f};

    const int srow = lane >> 3;
    const int kgx  = (lane & 7) ^ srow;
    const int rsw  = l16 & 7;

    for (int c = 0; c < 8; ++c) {
        const int ka = (c >> 1) << 6;
        const int kb = ((c & 1) << 8) + ka;
        const bool stA = !(c & 1);
        if (c) __syncthreads();
#pragma unroll
        for (int i = 0; i < 4; ++i) {
            const int rr = w * 32 + i * 8;
            if (stA)
                gl_lds16(Ph + (size_t)(row0 + rr + srow) * 256 + ka + kgx * 8, &sA[rr * 64]);
            gl_lds16(Bt + (size_t)(col0 + rr + srow) * 512 + kb + kgx * 8, &sB[rr * 64]);
        }
        __syncthreads();
#pragma unroll
        for (int ks = 0; ks < 2; ++ks) {
            const int kq = ks * 4 + quad;
            half8 af[4], bfr[4];
#pragma unroll
            for (int rt = 0; rt < 4; ++rt) {
                const int r = wr * 64 + rt * 16 + l16;
                af[rt] = *(const half8*)&sA[r * 64 + ((kq ^ rsw) << 3)];
            }
#pragma unroll
            for (int ct = 0; ct < 4; ++ct) {
                const int n = wc * 64 + ct * 16 + l16;
                bfr[ct] = *(const half8*)&sB[n * 64 + ((kq ^ rsw) << 3)];
            }
#pragma unroll
            for (int ct = 0; ct < 4; ++ct)
#pragma unroll
                for (int rt = 0; rt < 4; ++rt)
                    acc[rt][ct] = __builtin_amdgcn_mfma_f32_16x16x32_f16(
                        af[rt], bfr[ct], acc[rt][ct], 0, 0, 0);
        }
    }

#pragma unroll
    for (int rt = 0; rt < 4; ++rt) {
#pragma unroll
        for (int i = 0; i < 4; ++i) {
            const int gr = row0 + wr * 64 + rt * 16 + quad * 4 + i;
            const float s = rowscale[gr];
#pragma unroll
            for (int ct = 0; ct < 4; ++ct) {
                const int gc = col0 + wc * 64 + ct * 16 + l16;
                out[(size_t)gr * 256 + gc] = f2h(acc[rt][ct][i] * s);
            }
        }
    }
}

// count pass also records each edge's slot within its dst row (perm).
__global__ void tg_count(const int* __restrict__ dst, int* __restrict__ deg,
                         int* __restrict__ perm, int E)
{
    const int e = blockIdx.x * blockDim.x + threadIdx.x;
    if (e < E) perm[e] = atomicAdd(&deg[dst[e]], 1);
}

__global__ void tg_dinv(const int* __restrict__ deg, float* __restrict__ dinv, int N)
{
    const int i = blockIdx.x * blockDim.x + threadIdx.x;
    if (i < N) dinv[i] = 1.f / sqrtf((float)(deg[i] + 1));  // +1 self-loop
}

__global__ void tg_scan1(const int* __restrict__ cnt, int* __restrict__ out,
                         int* __restrict__ sums, int N)
{
    __shared__ int tmp[1024];
    const int t = threadIdx.x;
    const int gid = blockIdx.x * 1024 + t;
    const int v = (gid < N) ? cnt[gid] : 0;
    tmp[t] = v;
    __syncthreads();
    for (int o = 1; o < 1024; o <<= 1) {
        const int add = (t >= o) ? tmp[t - o] : 0;
        __syncthreads();
        tmp[t] += add;
        __syncthreads();
    }
    if (gid < N) out[gid] = tmp[t] - v;
    if (t == 1023) sums[blockIdx.x] = tmp[t];
}

__global__ void tg_scan2(int* __restrict__ sums, int nb)
{
    __shared__ int tmp[1024];
    const int t = threadIdx.x;
    const int v = (t < nb) ? sums[t] : 0;
    tmp[t] = v;
    __syncthreads();
    for (int o = 1; o < 1024; o <<= 1) {
        const int add = (t >= o) ? tmp[t - o] : 0;
        __syncthreads();
        tmp[t] += add;
        __syncthreads();
    }
    if (t < nb) sums[t] = tmp[t] - v;
}

__global__ void tg_scan3(int* __restrict__ rowptr, const int* __restrict__ offs,
                         int N, int E)
{
    const int gid = blockIdx.x * 1024 + threadIdx.x;
    if (gid < N) rowptr[gid] += offs[gid >> 10];
    else if (gid == N) rowptr[N] = E;
}

// atomic-free fill using perm from the count pass
__global__ void tg_fill(const int* __restrict__ src, const int* __restrict__ dst,
                        const int* __restrict__ rowptr, const int* __restrict__ perm,
                        int* __restrict__ col, int E)
{
    const int e = blockIdx.x * blockDim.x + threadIdx.x;
    if (e >= E) return;
    col[rowptr[dst[e]] + perm[e]] = src[e];
}

// out = relu(dinv[i]*(hwp[i] + sum hwp[src]) + bias): f16 in, single f16 out.
// 2 rows/wave, 32 lanes/row, 16B dwordx4 gathers, index double-buffer.
// Measured fabric-concurrency-bound (3.85 TB/s, invariant to structure).
__global__ void tg_aggregate_h(const unsigned short* __restrict__ hwpb,
                               const int* __restrict__ rowptr, const int* __restrict__ col,
                               const float* __restrict__ dinv, const float* __restrict__ bias,
                               unsigned short* __restrict__ hh, int N)
{
    const int gt = blockIdx.x * blockDim.x + threadIdx.x;
    const int row = gt >> 5;               // 32-thread group per row
    if (row >= N) return;
    const int hl = gt & 31;
    const int c = hl * 8;                  // 8 halves = 16 B per lane

    const unsigned short* base = hwpb + c;
    const int beg = rowptr[row], end = rowptr[row + 1];

    const us8 sv = *(const us8*)(base + (size_t)row * 256);
    float a[8];
#pragma unroll
    for (int j = 0; j < 8; ++j) a[j] = h2f(sv[j]);

    int p = beg;
    int rem = end - beg;
    int c0[8];
    if (rem >= 8) {
#pragma unroll
        for (int u = 0; u < 8; ++u) c0[u] = col[p + u];
    }
    while (rem >= 8) {
        int c1[8];
        const bool more = rem >= 16;
        if (more) {
#pragma unroll
            for (int u = 0; u < 8; ++u) c1[u] = col[p + 8 + u];
        }
        us8 v[8];
#pragma unroll
        for (int u = 0; u < 8; ++u)
            v[u] = *(const us8*)(base + (size_t)c0[u] * 256);
#pragma unroll
        for (int u = 0; u < 8; ++u)
#pragma unroll
            for (int j = 0; j < 8; ++j) a[j] += h2f(v[u][j]);
        if (more) {
#pragma unroll
            for (int u = 0; u < 8; ++u) c0[u] = c1[u];
        }
        p += 8; rem -= 8;
    }
    if (rem > 0) {
        const int last = end - 1;
        int ci[8];
#pragma unroll
        for (int u = 0; u < 8; ++u) {
            const int pp = (p + u < last) ? p + u : last;   // clamp: no OOB
            ci[u] = col[pp];
        }
        us8 v[8];
#pragma unroll
        for (int u = 0; u < 8; ++u)
            v[u] = *(const us8*)(base + (size_t)(u < rem ? ci[u] : row) * 256);
#pragma unroll
        for (int u = 0; u < 8; ++u) {
            if (u < rem) {
#pragma unroll
                for (int j = 0; j < 8; ++j) a[j] += h2f(v[u][j]);
            }
        }
    }

    const float di = dinv[row];
    const float4 b0 = *(const float4*)&bias[c];
    const float4 b1 = *(const float4*)&bias[c + 4];
    us8 o;
    o[0] = f2h(fmaxf(di * a[0] + b0.x, 0.f));
    o[1] = f2h(fmaxf(di * a[1] + b0.y, 0.f));
    o[2] = f2h(fmaxf(di * a[2] + b0.z, 0.f));
    o[3] = f2h(fmaxf(di * a[3] + b0.w, 0.f));
    o[4] = f2h(fmaxf(di * a[4] + b1.x, 0.f));
    o[5] = f2h(fmaxf(di * a[5] + b1.y, 0.f));
    o[6] = f2h(fmaxf(di * a[6] + b1.z, 0.f));
    o[7] = f2h(fmaxf(di * a[7] + b1.w, 0.f));
    *(us8*)&hh[(size_t)row * 256 + c] = o;
}

__global__ void tg_ranges(const int* __restrict__ batch, int* __restrict__ starts,
                          int N, int G)
{
    const int g = blockIdx.x * blockDim.x + threadIdx.x;
    if (g > G) return;
    int lo = 0, hi = N;
    while (lo < hi) {
        const int mid = (lo + hi) >> 1;
        if (batch[mid] < g) lo = mid + 1; else hi = mid;
    }
    starts[g] = lo;
}

// Mean-pool: block per graph, 4 waves split rows, lane owns 4 channels.
__global__ void tg_pool(const unsigned short* __restrict__ hh,
                        const int* __restrict__ starts, float* __restrict__ pooled, int G)
{
    __shared__ float sh[4][64][4];
    const int g = blockIdx.x;
    const int t = threadIdx.x;
    const int wv = t >> 6, lane = t & 63;
    const int c = lane * 4;
    const int beg = starts[g], end = starts[g + 1];
    float s0 = 0.f, s1 = 0.f, s2 = 0.f, s3 = 0.f;
    for (int r = beg + wv; r < end; r += 4) {
        const ushort4 vh = *(const ushort4*)&hh[(size_t)r * 256 + c];
        s0 += h2f(vh.x); s1 += h2f(vh.y); s2 += h2f(vh.z); s3 += h2f(vh.w);
    }
    sh[wv][lane][0] = s0; sh[wv][lane][1] = s1;
    sh[wv][lane][2] = s2; sh[wv][lane][3] = s3;
    __syncthreads();
    if (t < 64) {
        const float inv = 1.f / fmaxf((float)(end - beg), 1.f);
        float4 o;
        o.x = (sh[0][t][0] + sh[1][t][0] + sh[2][t][0] + sh[3][t][0]) * inv;
        o.y = (sh[0][t][1] + sh[1][t][1] + sh[2][t][1] + sh[3][t][1]) * inv;
        o.z = (sh[0][t][2] + sh[1][t][2] + sh[2][t][2] + sh[3][t][2]) * inv;
        o.w = (sh[0][t][3] + sh[1][t][3] + sh[2][t][3] + sh[3][t][3]) * inv;
        *(float4*)&pooled[(size_t)g * 256 + t * 4] = o;
    }
}

__global__ void tg_mlp(const float* __restrict__ A, const float* __restrict__ B,
                       const float* __restrict__ bias, float* __restrict__ Cout,
                       int M, int K, int Nc, int do_relu)
{
    const int idx = blockIdx.x * blockDim.x + threadIdx.x;
    if (idx >= M * Nc) return;
    const int m = idx / Nc;
    const int n = idx - m * Nc;
    float acc = 0.f;
    for (int k = 0; k < K; ++k) acc += A[(size_t)m * K + k] * B[(size_t)k * Nc + n];
    acc += bias[n];
    Cout[idx] = do_relu ? fmaxf(acc, 0.f) : acc;
}

extern "C" void kernel_launch(void* const* d_in, const int* in_sizes, int n_in,
                              void* d_out, int out_size, void* d_ws, size_t ws_size,
                              hipStream_t stream)
{
    const float* x    = (const float*)d_in[0];
    const float* W_ft = (const float*)d_in[1];
    const float* b_ft = (const float*)d_in[2];
    const float* ln_g = (const float*)d_in[3];
    const float* ln_b = (const float*)d_in[4];
    const float* W_g[3] = {(const float*)d_in[5], (const float*)d_in[7], (const float*)d_in[9]};
    const float* b_g[3] = {(const float*)d_in[6], (const float*)d_in[8], (const float*)d_in[10]};
    const float* W_c0 = (const float*)d_in[11];
    const float* b_c0 = (const float*)d_in[12];
    const float* W_c1 = (const float*)d_in[13];
    const float* b_c1 = (const float*)d_in[14];
    const float* W_c2 = (const float*)d_in[15];
    const float* b_c2 = (const float*)d_in[16];
    const int*   edge  = (const int*)d_in[17];
    const int*   batch = (const int*)d_in[18];

    const int N    = in_sizes[18];        // 100000
    const int E    = in_sizes[17] / 2;    // 1600000
    const int Mpad = (N + 127) & ~127;    // 100096
    const int H2   = in_sizes[14];        // 128
    const int Cc   = in_sizes[15] / H2;   // 4
    const int G    = out_size / Cc;       // 512

    const int* srcI = edge;
    const int* dstI = edge + E;

    size_t off = 0;
    auto alloc = [&](size_t bytes) {
        char* p = (char*)d_ws + off;
        off = (off + bytes + 255) & ~(size_t)255;
        return p;
    };
    unsigned short* hh   = (unsigned short*)alloc((size_t)Mpad * 256 * 2);
    unsigned short* hwpb = (unsigned short*)alloc((size_t)Mpad * 256 * 2);
    float* dinv   = (float*)alloc((size_t)Mpad * 4);
    int*   deg    = (int*)alloc((size_t)Mpad * 4);
    int*   rowptr = (int*)alloc((size_t)(N + 1) * 4);
    int*   perm   = (int*)alloc((size_t)E * 4);
    int*   col    = (int*)alloc((size_t)E * 4);
    int*   bsums  = (int*)alloc(1024 * 4);
    int*   starts = (int*)alloc((size_t)(G + 1) * 4);
    float* pooled = (float*)alloc((size_t)G * 256 * 4);
    float* z0     = (float*)alloc((size_t)G * 256 * 4);
    float* z1     = (float*)alloc((size_t)G * H2 * 4);
    unsigned short* Bt[4];
    for (int i = 0; i < 4; ++i)
        Bt[i] = (unsigned short*)alloc((size_t)256 * 512 * 2);
    (void)ws_size; (void)n_in;

    hipMemsetAsync(deg, 0, (size_t)Mpad * 4, stream);
    // zero pad rows of h plane (read by GCN GEMM A staging)
    hipMemsetAsync(hh + (size_t)N * 256, 0, (size_t)(Mpad - N) * 256 * 2, stream);

    // 0. weight prep
    tg_splitB<<<dim3(4, 4, 4), dim3(256), 0, stream>>>(
        W_ft, W_g[0], W_g[1], W_g[2], Bt[0], Bt[1], Bt[2], Bt[3]);

    // 1. fused feature transform + LayerNorm + PE -> single f16 h plane
    tg_ft_ln<<<dim3(Mpad / 128), dim3(256), 0, stream>>>(
        x, Bt[0], b_ft, ln_g, ln_b, hh, N);

    // 2. degrees + CSR build (rows = dst, cols = src)
    tg_count<<<dim3((E + 255) / 256), dim3(256), 0, stream>>>(dstI, deg, perm, E);
    tg_dinv<<<dim3((Mpad + 255) / 256), dim3(256), 0, stream>>>(deg, dinv, Mpad);
    const int NB = (N + 1023) / 1024;
    tg_scan1<<<dim3(NB), dim3(1024), 0, stream>>>(deg, rowptr, bsums, N);
    tg_scan2<<<dim3(1), dim3(1024), 0, stream>>>(bsums, NB);
    tg_scan3<<<dim3((N + 1024) / 1024), dim3(1024), 0, stream>>>(rowptr, bsums, N, E);
    tg_fill<<<dim3((E + 255) / 256), dim3(256), 0, stream>>>(srcI, dstI, rowptr, perm, col, E);

    // 3. GCN layers
    const int nbx = (Mpad / 128) * 2;     // 1-D grid: lg>>1 = row tile, lg&1 = col tile
    for (int l = 0; l < 3; ++l) {
        tg_gemm<<<dim3(nbx), dim3(256), 0, stream>>>(hh, Bt[l + 1], dinv, hwpb);
        tg_aggregate_h<<<dim3((N + 7) / 8), dim3(256), 0, stream>>>(hwpb, rowptr, col, dinv,
                                                                    b_g[l], hh, N);
    }

    // 4. per-graph mean pool
    tg_ranges<<<dim3((G + 256) / 256), dim3(256), 0, stream>>>(batch, starts, N, G);
    tg_pool<<<dim3(G), dim3(256), 0, stream>>>(hh, starts, pooled, G);

    // 5. classifier MLP
    tg_mlp<<<dim3((G * 256 + 255) / 256), dim3(256), 0, stream>>>(pooled, W_c0, b_c0, z0, G, 256, 256, 1);
    tg_mlp<<<dim3((G * H2 + 255) / 256), dim3(256), 0, stream>>>(z0, W_c1, b_c1, z1, G, 256, H2, 1);
    tg_mlp<<<dim3((G * Cc + 255) / 256), dim3(256), 0, stream>>>(z1, W_c2, b_c2, (float*)d_out, G, H2, Cc, 0);
}

// Round 3
// 1061.215 us; speedup vs baseline: 1.1169x; 1.0282x over previous
//
#include <hip/hip_runtime.h>
#include <math.h>

// ---------------------------------------------------------------------------
// Temporal GNN. Round 10:
//  * tg_ft_ln epilogue rewritten: LN+PE applied directly in the MFMA
//    accumulator layout (no f32 LDS round-trip, no rolled pass, no extra
//    barriers). PE trig = Cody-Waite 3-term reduction + hardware
//    v_sin/v_cos (ang computed as fl(row*div) to match reference rounding;
//    div via libm expf into a 128-entry LDS table, matching XLA exactly).
//    Odd cols use v_cos of the reduced angle (better than sin(ang+pi/2)).
//  * B staging issued before the dependent A f32->f16 chain (MLP overlap).
//  * Everything else = round 9 (fused FT+LN+PE, perm-based CSR, aggregate
//    at its measured fabric-concurrency floor, A-resident GCN GEMM).
// ---------------------------------------------------------------------------

typedef __attribute__((ext_vector_type(8))) _Float16 half8;  // MFMA A/B frag
typedef __attribute__((ext_vector_type(4))) float floatx4;   // MFMA C/D
typedef __attribute__((ext_vector_type(8))) unsigned short us8; // 16B f16 vec

union HU { _Float16 h; unsigned short u; };

static __device__ __forceinline__ unsigned short f2h(float f) {
    HU x; x.h = (_Float16)f; return x.u;          // v_cvt_f16_f32 (RNE)
}
static __device__ __forceinline__ float h2f(unsigned short s) {
    HU x; x.u = s; return (float)x.h;
}

// async 16B/lane global -> LDS (dest = wave-uniform base + lane*16)
static __device__ __forceinline__ void gl_lds16(const void* g, void* l) {
    __builtin_amdgcn_global_load_lds(
        (const __attribute__((address_space(1))) unsigned int*)(g),
        (__attribute__((address_space(3))) unsigned int*)(l), 16, 0, 0);
}

// sin/cos(ang) for ang up to ~1e5 rad: Cody-Waite 3-term reduction
// (k <= 2^14; C1 mantissa 9 bits -> k*C1 exact; fma single-rounding for
// C2/C3 terms; abs err ~2.5e-6 rad) + hardware trig on revolutions.
static __device__ __forceinline__ float cw_trig(float ang, bool is_cos) {
    const float i2pi = 0.15915494309189535f;
    const float k = rintf(ang * i2pi);
    float r = fmaf(k, -6.28125f, ang);
    r = fmaf(k, -1.9352436065673828e-3f, r);
    r = fmaf(k, -6.3573019e-8f, r);
    const float rv = r * i2pi;
    return is_cos ? __builtin_amdgcn_cosf(rv) : __builtin_amdgcn_sinf(rv);
}

// Split W[256][256] (k-major) into Bt'[n][512] = [Bh | Bl] f16 (transposed).
// grid (4,4,4): z = weight index.
__global__ void tg_splitB(const float* __restrict__ W0, const float* __restrict__ W1,
                          const float* __restrict__ W2, const float* __restrict__ W3,
                          unsigned short* __restrict__ B0, unsigned short* __restrict__ B1,
                          unsigned short* __restrict__ B2, unsigned short* __restrict__ B3)
{
    const float* Ws[4] = {W0, W1, W2, W3};
    unsigned short* Bs[4] = {B0, B1, B2, B3};
    const float* W = Ws[blockIdx.z];
    unsigned short* Bt = Bs[blockIdx.z];

    __shared__ float T[64][68];
    const int tk = blockIdx.x * 64, tn = blockIdx.y * 64;
    const int t = threadIdx.x;
#pragma unroll
    for (int j = 0; j < 4; ++j) {
        const int idx = t + 256 * j;
        const int k = idx >> 4, c4 = (idx & 15) * 4;
        const float4 v = *(const float4*)&W[(size_t)(tk + k) * 256 + tn + c4];
        T[k][c4] = v.x; T[k][c4 + 1] = v.y; T[k][c4 + 2] = v.z; T[k][c4 + 3] = v.w;
    }
    __syncthreads();
#pragma unroll
    for (int j = 0; j < 4; ++j) {
        const int idx = t + 256 * j;
        const int n = idx >> 4, q = (idx & 15) * 4;
        unsigned short hh[4], ll[4];
#pragma unroll
        for (int i = 0; i < 4; ++i) {
            const float f = T[q + i][n];
            hh[i] = f2h(f);
            ll[i] = f2h(f - h2f(hh[i]));
        }
        uint2 hp, lp;
        hp.x = (unsigned)hh[0] | ((unsigned)hh[1] << 16);
        hp.y = (unsigned)hh[2] | ((unsigned)hh[3] << 16);
        lp.x = (unsigned)ll[0] | ((unsigned)ll[1] << 16);
        lp.y = (unsigned)ll[2] | ((unsigned)ll[3] << 16);
        unsigned short* row = Bt + (size_t)(tn + n) * 512;
        *(uint2*)&row[tk + q]       = hp;   // Bh
        *(uint2*)&row[256 + tk + q] = lp;   // Bl
    }
}

// ---------------------------------------------------------------------------
// Fused FT GEMM + LayerNorm + PE. Tile 128 rows x 256 cols, 4 waves (2x2),
// wave tile 64x128, acc[4][8]. Per ka chunk (K=64):
//   issue sB = Bh(ka) async; stage A (f32 x -> hi/lo f16 regs -> ds_write)
//   P0/P1: acc += Ah.Bh + Al.Bh
//   stage sB = Bl ; P2: acc += Ah.Bl
// Epilogue: stats via 16-lane shfl + LDS; then LN+PE applied directly in
// accumulator layout with Cody-Waite hw trig, strided f16 stores.
// ---------------------------------------------------------------------------
__global__ __launch_bounds__(256, 2)
void tg_ft_ln(const float* __restrict__ x, const unsigned short* __restrict__ Bt,
              const float* __restrict__ bias, const float* __restrict__ lng,
              const float* __restrict__ lnb, unsigned short* __restrict__ hh, int N)
{
    __shared__ unsigned short sAh[128 * 64];   // 16 KB
    __shared__ unsigned short sAl[128 * 64];   // 16 KB
    __shared__ unsigned short sB[256 * 64];    // 32 KB (Bh then Bl)
    __shared__ float sStats[128][2][2];        // [row][wc][{sum,sumsq}] 2 KB
    __shared__ float sDiv[128];                // PE div table (512 B)

    const int t = threadIdx.x;
    const int w = t >> 6, lane = t & 63;
    const int quad = lane >> 4, l16 = lane & 15;
    const int wr = w >> 1, wc = w & 1;
    const int row0 = blockIdx.x * 128;

    // PE div table: matches reference jnp.exp(arange(0,256,2) * cexp) (f32)
    if (t < 128) sDiv[t] = expf((float)(2 * t) * -0.035977892078031970f);

    floatx4 acc[4][8];
#pragma unroll
    for (int i = 0; i < 4; ++i)
#pragma unroll
        for (int j = 0; j < 8; ++j) acc[i][j] = (floatx4){0.f, 0.f, 0.f, 0.f};

    // A staging map: thread -> (row, half); 4 slots (k-groups of 8) each
    const int arow = t >> 1;
    const int ahalf = t & 1;
    // B staging map (gl_lds16): 8 lanes/row, slot (lane&7) holds kg = slot^(row&7)
    const int srow = lane >> 3;
    const int kgx  = (lane & 7) ^ srow;
    const int rsw  = l16 & 7;

    for (int k4 = 0; k4 < 4; ++k4) {
        const int ka = k4 * 64;
        if (k4) __syncthreads();
        // --- issue sB = Bh(ka) first (async, overlaps the A chain) ---
#pragma unroll
        for (int i = 0; i < 8; ++i) {
            const int rr = w * 64 + i * 8;
            gl_lds16(Bt + (size_t)(rr + srow) * 512 + ka + kgx * 8, &sB[rr * 64]);
        }
        // --- stage A: read f32 x, split to hi/lo f16, swizzled ds_write ---
        {
            const int grow = row0 + arow;
            const bool ok = grow < N;
            const float* xp = x + (size_t)grow * 256 + ka + ahalf * 32;
#pragma unroll
            for (int j = 0; j < 4; ++j) {
                const int kg = ahalf * 4 + j;
                float4 v0 = {0.f, 0.f, 0.f, 0.f}, v1 = {0.f, 0.f, 0.f, 0.f};
                if (ok) {
                    v0 = *(const float4*)(xp + j * 8);
                    v1 = *(const float4*)(xp + j * 8 + 4);
                }
                const float f[8] = {v0.x, v0.y, v0.z, v0.w, v1.x, v1.y, v1.z, v1.w};
                us8 hi, lo;
#pragma unroll
                for (int i = 0; i < 8; ++i) {
                    hi[i] = f2h(f[i]);
                    lo[i] = f2h(f[i] - h2f(hi[i]));
                }
                const int ad = arow * 64 + ((kg ^ (arow & 7)) << 3);
                *(us8*)&sAh[ad] = hi;
                *(us8*)&sAl[ad] = lo;
            }
        }
        __syncthreads();
        // --- P0 + P1: Ah.Bh + Al.Bh ---
#pragma unroll
        for (int ks = 0; ks < 2; ++ks) {
            const int kq = ks * 4 + quad;
            half8 afh[4], afl[4];
#pragma unroll
            for (int rt = 0; rt < 4; ++rt) {
                const int r = wr * 64 + rt * 16 + l16;
                const int off = r * 64 + ((kq ^ rsw) << 3);
                afh[rt] = *(const half8*)&sAh[off];
                afl[rt] = *(const half8*)&sAl[off];
            }
#pragma unroll
            for (int cb = 0; cb < 2; ++cb) {
                half8 bfr[4];
#pragma unroll
                for (int c4 = 0; c4 < 4; ++c4) {
                    const int n = wc * 128 + (cb * 4 + c4) * 16 + l16;
                    bfr[c4] = *(const half8*)&sB[n * 64 + ((kq ^ rsw) << 3)];
                }
#pragma unroll
                for (int c4 = 0; c4 < 4; ++c4)
#pragma unroll
                    for (int rt = 0; rt < 4; ++rt) {
                        acc[rt][cb * 4 + c4] = __builtin_amdgcn_mfma_f32_16x16x32_f16(
                            afh[rt], bfr[c4], acc[rt][cb * 4 + c4], 0, 0, 0);
                        acc[rt][cb * 4 + c4] = __builtin_amdgcn_mfma_f32_16x16x32_f16(
                            afl[rt], bfr[c4], acc[rt][cb * 4 + c4], 0, 0, 0);
                    }
            }
        }
        __syncthreads();
        // --- stage sB = Bl(ka) ---
#pragma unroll
        for (int i = 0; i < 8; ++i) {
            const int rr = w * 64 + i * 8;
            gl_lds16(Bt + (size_t)(rr + srow) * 512 + 256 + ka + kgx * 8, &sB[rr * 64]);
        }
        __syncthreads();
        // --- P2: Ah.Bl ---
#pragma unroll
        for (int ks = 0; ks < 2; ++ks) {
            const int kq = ks * 4 + quad;
            half8 afh[4];
#pragma unroll
            for (int rt = 0; rt < 4; ++rt) {
                const int r = wr * 64 + rt * 16 + l16;
                afh[rt] = *(const half8*)&sAh[r * 64 + ((kq ^ rsw) << 3)];
            }
#pragma unroll
            for (int cb = 0; cb < 2; ++cb) {
                half8 bfr[4];
#pragma unroll
                for (int c4 = 0; c4 < 4; ++c4) {
                    const int n = wc * 128 + (cb * 4 + c4) * 16 + l16;
                    bfr[c4] = *(const half8*)&sB[n * 64 + ((kq ^ rsw) << 3)];
                }
#pragma unroll
                for (int c4 = 0; c4 < 4; ++c4)
#pragma unroll
                    for (int rt = 0; rt < 4; ++rt)
                        acc[rt][cb * 4 + c4] = __builtin_amdgcn_mfma_f32_16x16x32_f16(
                            afh[rt], bfr[c4], acc[rt][cb * 4 + c4], 0, 0, 0);
            }
        }
    }

    // --- per-thread column constants ---
    float bs[8], gs[8], bv[8], dv[8];
#pragma unroll
    for (int ct = 0; ct < 8; ++ct) {
        const int gc = wc * 128 + ct * 16 + l16;
        bs[ct] = bias[gc]; gs[ct] = lng[gc]; bv[ct] = lnb[gc];
        dv[ct] = sDiv[gc >> 1];
    }

    // --- stats: v = relu(acc + bias), per-row sum/sumsq over wave's 128 cols
#pragma unroll
    for (int rt = 0; rt < 4; ++rt) {
#pragma unroll
        for (int i = 0; i < 4; ++i) {
            float s = 0.f, q = 0.f;
#pragma unroll
            for (int ct = 0; ct < 8; ++ct) {
                const float v = fmaxf(acc[rt][ct][i] + bs[ct], 0.f);
                s += v; q += v * v;
            }
#pragma unroll
            for (int m = 1; m < 16; m <<= 1) {
                s += __shfl_xor(s, m, 64);
                q += __shfl_xor(q, m, 64);
            }
            if (l16 == 0) {
                const int rl = wr * 64 + rt * 16 + quad * 4 + i;
                sStats[rl][wc][0] = s;
                sStats[rl][wc][1] = q;
            }
        }
    }
    __syncthreads();

    // --- LN + PE directly in accumulator layout, strided f16 stores ---
    const bool is_cos = (l16 & 1);
#pragma unroll
    for (int rt = 0; rt < 4; ++rt) {
#pragma unroll
        for (int i = 0; i < 4; ++i) {
            const int rl = wr * 64 + rt * 16 + quad * 4 + i;
            const int gr = row0 + rl;
            if (gr >= N) continue;
            const float sum = sStats[rl][0][0] + sStats[rl][1][0];
            const float sq  = sStats[rl][0][1] + sStats[rl][1][1];
            const float mu  = sum * (1.f / 256.f);
            const float var = sq * (1.f / 256.f) - mu * mu;
            const float rstd = 1.f / sqrtf(var + 1e-5f);
            const float rf = (float)gr;
            unsigned short* orow = hh + (size_t)gr * 256 + wc * 128 + l16;
#pragma unroll
            for (int ct = 0; ct < 8; ++ct) {
                const float v = fmaxf(acc[rt][ct][i] + bs[ct], 0.f);
                const float nrm = (v - mu) * rstd * gs[ct] + bv[ct];
                const float pe = cw_trig(rf * dv[ct], is_cos);
                orow[ct * 16] = f2h(nrm + pe);
            }
        }
    }
}

// GCN GEMM: A-resident chunk order, XCD-paired col tiles.
// hwp = f16((h@W) * dinv_row), K'=512 = Bh|Bl against single-plane A.
__global__ __launch_bounds__(256, 3)
void tg_gemm(const unsigned short* __restrict__ Ph,
             const unsigned short* __restrict__ Bt,
             const float* __restrict__ rowscale,
             unsigned short* __restrict__ out)
{
    __shared__ unsigned short sA[128 * 64], sB[128 * 64];  // 16 KB each

    const int t = threadIdx.x;
    const int w = t >> 6, lane = t & 63;
    const int quad = lane >> 4, l16 = lane & 15;
    const int wr = w >> 1, wc = w & 1;

    // bijective chunked XCD swizzle: (bx,0)/(bx,1) pairs co-resident on one XCD
    const int nwg = gridDim.x;
    const int swq = nwg >> 3, swr = nwg & 7;
    const int xcd = blockIdx.x & 7, oidx = blockIdx.x >> 3;
    const int lg = (xcd < swr ? xcd * (swq + 1)
                              : swr * (swq + 1) + (xcd - swr) * swq) + oidx;
    const int row0 = (lg >> 1) * 128;
    const int col0 = (lg & 1) * 128;

    floatx4 acc[4][4];
#pragma unroll
    for (int i = 0; i < 4; ++i)
#pragma unroll
        for (int j = 0; j < 4; ++j) acc[i][j] = (floatx4){0.f, 0.f, 0.f, 0.f};

    const int srow = lane >> 3;
    const int kgx  = (lane & 7) ^ srow;
    const int rsw  = l16 & 7;

    for (int c = 0; c < 8; ++c) {
        const int ka = (c >> 1) << 6;
        const int kb = ((c & 1) << 8) + ka;
        const bool stA = !(c & 1);
        if (c) __syncthreads();
#pragma unroll
        for (int i = 0; i < 4; ++i) {
            const int rr = w * 32 + i * 8;
            if (stA)
                gl_lds16(Ph + (size_t)(row0 + rr + srow) * 256 + ka + kgx * 8, &sA[rr * 64]);
            gl_lds16(Bt + (size_t)(col0 + rr + srow) * 512 + kb + kgx * 8, &sB[rr * 64]);
        }
        __syncthreads();
#pragma unroll
        for (int ks = 0; ks < 2; ++ks) {
            const int kq = ks * 4 + quad;
            half8 af[4], bfr[4];
#pragma unroll
            for (int rt = 0; rt < 4; ++rt) {
                const int r = wr * 64 + rt * 16 + l16;
                af[rt] = *(const half8*)&sA[r * 64 + ((kq ^ rsw) << 3)];
            }
#pragma unroll
            for (int ct = 0; ct < 4; ++ct) {
                const int n = wc * 64 + ct * 16 + l16;
                bfr[ct] = *(const half8*)&sB[n * 64 + ((kq ^ rsw) << 3)];
            }
#pragma unroll
            for (int ct = 0; ct < 4; ++ct)
#pragma unroll
                for (int rt = 0; rt < 4; ++rt)
                    acc[rt][ct] = __builtin_amdgcn_mfma_f32_16x16x32_f16(
                        af[rt], bfr[ct], acc[rt][ct], 0, 0, 0);
        }
    }

#pragma unroll
    for (int rt = 0; rt < 4; ++rt) {
#pragma unroll
        for (int i = 0; i < 4; ++i) {
            const int gr = row0 + wr * 64 + rt * 16 + quad * 4 + i;
            const float s = rowscale[gr];
#pragma unroll
            for (int ct = 0; ct < 4; ++ct) {
                const int gc = col0 + wc * 64 + ct * 16 + l16;
                out[(size_t)gr * 256 + gc] = f2h(acc[rt][ct][i] * s);
            }
        }
    }
}

// count pass also records each edge's slot within its dst row (perm).
__global__ void tg_count(const int* __restrict__ dst, int* __restrict__ deg,
                         int* __restrict__ perm, int E)
{
    const int e = blockIdx.x * blockDim.x + threadIdx.x;
    if (e < E) perm[e] = atomicAdd(&deg[dst[e]], 1);
}

__global__ void tg_dinv(const int* __restrict__ deg, float* __restrict__ dinv, int N)
{
    const int i = blockIdx.x * blockDim.x + threadIdx.x;
    if (i < N) dinv[i] = 1.f / sqrtf((float)(deg[i] + 1));  // +1 self-loop
}

__global__ void tg_scan1(const int* __restrict__ cnt, int* __restrict__ out,
                         int* __restrict__ sums, int N)
{
    __shared__ int tmp[1024];
    const int t = threadIdx.x;
    const int gid = blockIdx.x * 1024 + t;
    const int v = (gid < N) ? cnt[gid] : 0;
    tmp[t] = v;
    __syncthreads();
    for (int o = 1; o < 1024; o <<= 1) {
        const int add = (t >= o) ? tmp[t - o] : 0;
        __syncthreads();
        tmp[t] += add;
        __syncthreads();
    }
    if (gid < N) out[gid] = tmp[t] - v;
    if (t == 1023) sums[blockIdx.x] = tmp[t];
}

__global__ void tg_scan2(int* __restrict__ sums, int nb)
{
    __shared__ int tmp[1024];
    const int t = threadIdx.x;
    const int v = (t < nb) ? sums[t] : 0;
    tmp[t] = v;
    __syncthreads();
    for (int o = 1; o < 1024; o <<= 1) {
        const int add = (t >= o) ? tmp[t - o] : 0;
        __syncthreads();
        tmp[t] += add;
        __syncthreads();
    }
    if (t < nb) sums[t] = tmp[t] - v;
}

__global__ void tg_scan3(int* __restrict__ rowptr, const int* __restrict__ offs,
                         int N, int E)
{
    const int gid = blockIdx.x * 1024 + threadIdx.x;
    if (gid < N) rowptr[gid] += offs[gid >> 10];
    else if (gid == N) rowptr[N] = E;
}

// atomic-free fill using perm from the count pass
__global__ void tg_fill(const int* __restrict__ src, const int* __restrict__ dst,
                        const int* __restrict__ rowptr, const int* __restrict__ perm,
                        int* __restrict__ col, int E)
{
    const int e = blockIdx.x * blockDim.x + threadIdx.x;
    if (e >= E) return;
    col[rowptr[dst[e]] + perm[e]] = src[e];
}

// out = relu(dinv[i]*(hwp[i] + sum hwp[src]) + bias): f16 in, single f16 out.
// 2 rows/wave, 32 lanes/row, 16B dwordx4 gathers, index double-buffer.
// Measured fabric-concurrency-bound (3.85 TB/s, invariant to structure).
__global__ void tg_aggregate_h(const unsigned short* __restrict__ hwpb,
                               const int* __restrict__ rowptr, const int* __restrict__ col,
                               const float* __restrict__ dinv, const float* __restrict__ bias,
                               unsigned short* __restrict__ hh, int N)
{
    const int gt = blockIdx.x * blockDim.x + threadIdx.x;
    const int row = gt >> 5;               // 32-thread group per row
    if (row >= N) return;
    const int hl = gt & 31;
    const int c = hl * 8;                  // 8 halves = 16 B per lane

    const unsigned short* base = hwpb + c;
    const int beg = rowptr[row], end = rowptr[row + 1];

    const us8 sv = *(const us8*)(base + (size_t)row * 256);
    float a[8];
#pragma unroll
    for (int j = 0; j < 8; ++j) a[j] = h2f(sv[j]);

    int p = beg;
    int rem = end - beg;
    int c0[8];
    if (rem >= 8) {
#pragma unroll
        for (int u = 0; u < 8; ++u) c0[u] = col[p + u];
    }
    while (rem >= 8) {
        int c1[8];
        const bool more = rem >= 16;
        if (more) {
#pragma unroll
            for (int u = 0; u < 8; ++u) c1[u] = col[p + 8 + u];
        }
        us8 v[8];
#pragma unroll
        for (int u = 0; u < 8; ++u)
            v[u] = *(const us8*)(base + (size_t)c0[u] * 256);
#pragma unroll
        for (int u = 0; u < 8; ++u)
#pragma unroll
            for (int j = 0; j < 8; ++j) a[j] += h2f(v[u][j]);
        if (more) {
#pragma unroll
            for (int u = 0; u < 8; ++u) c0[u] = c1[u];
        }
        p += 8; rem -= 8;
    }
    if (rem > 0) {
        const int last = end - 1;
        int ci[8];
#pragma unroll
        for (int u = 0; u < 8; ++u) {
            const int pp = (p + u < last) ? p + u : last;   // clamp: no OOB
            ci[u] = col[pp];
        }
        us8 v[8];
#pragma unroll
        for (int u = 0; u < 8; ++u)
            v[u] = *(const us8*)(base + (size_t)(u < rem ? ci[u] : row) * 256);
#pragma unroll
        for (int u = 0; u < 8; ++u) {
            if (u < rem) {
#pragma unroll
                for (int j = 0; j < 8; ++j) a[j] += h2f(v[u][j]);
            }
        }
    }

    const float di = dinv[row];
    const float4 b0 = *(const float4*)&bias[c];
    const float4 b1 = *(const float4*)&bias[c + 4];
    us8 o;
    o[0] = f2h(fmaxf(di * a[0] + b0.x, 0.f));
    o[1] = f2h(fmaxf(di * a[1] + b0.y, 0.f));
    o[2] = f2h(fmaxf(di * a[2] + b0.z, 0.f));
    o[3] = f2h(fmaxf(di * a[3] + b0.w, 0.f));
    o[4] = f2h(fmaxf(di * a[4] + b1.x, 0.f));
    o[5] = f2h(fmaxf(di * a[5] + b1.y, 0.f));
    o[6] = f2h(fmaxf(di * a[6] + b1.z, 0.f));
    o[7] = f2h(fmaxf(di * a[7] + b1.w, 0.f));
    *(us8*)&hh[(size_t)row * 256 + c] = o;
}

__global__ void tg_ranges(const int* __restrict__ batch, int* __restrict__ starts,
                          int N, int G)
{
    const int g = blockIdx.x * blockDim.x + threadIdx.x;
    if (g > G) return;
    int lo = 0, hi = N;
    while (lo < hi) {
        const int mid = (lo + hi) >> 1;
        if (batch[mid] < g) lo = mid + 1; else hi = mid;
    }
    starts[g] = lo;
}

// Mean-pool: block per graph, 4 waves split rows, lane owns 4 channels.
__global__ void tg_pool(const unsigned short* __restrict__ hh,
                        const int* __restrict__ starts, float* __restrict__ pooled, int G)
{
    __shared__ float sh[4][64][4];
    const int g = blockIdx.x;
    const int t = threadIdx.x;
    const int wv = t >> 6, lane = t & 63;
    const int c = lane * 4;
    const int beg = starts[g], end = starts[g + 1];
    float s0 = 0.f, s1 = 0.f, s2 = 0.f, s3 = 0.f;
    for (int r = beg + wv; r < end; r += 4) {
        const ushort4 vh = *(const ushort4*)&hh[(size_t)r * 256 + c];
        s0 += h2f(vh.x); s1 += h2f(vh.y); s2 += h2f(vh.z); s3 += h2f(vh.w);
    }
    sh[wv][lane][0] = s0; sh[wv][lane][1] = s1;
    sh[wv][lane][2] = s2; sh[wv][lane][3] = s3;
    __syncthreads();
    if (t < 64) {
        const float inv = 1.f / fmaxf((float)(end - beg), 1.f);
        float4 o;
        o.x = (sh[0][t][0] + sh[1][t][0] + sh[2][t][0] + sh[3][t][0]) * inv;
        o.y = (sh[0][t][1] + sh[1][t][1] + sh[2][t][1] + sh[3][t][1]) * inv;
        o.z = (sh[0][t][2] + sh[1][t][2] + sh[2][t][2] + sh[3][t][2]) * inv;
        o.w = (sh[0][t][3] + sh[1][t][3] + sh[2][t][3] + sh[3][t][3]) * inv;
        *(float4*)&pooled[(size_t)g * 256 + t * 4] = o;
    }
}

__global__ void tg_mlp(const float* __restrict__ A, const float* __restrict__ B,
                       const float* __restrict__ bias, float* __restrict__ Cout,
                       int M, int K, int Nc, int do_relu)
{
    const int idx = blockIdx.x * blockDim.x + threadIdx.x;
    if (idx >= M * Nc) return;
    const int m = idx / Nc;
    const int n = idx - m * Nc;
    float acc = 0.f;
    for (int k = 0; k < K; ++k) acc += A[(size_t)m * K + k] * B[(size_t)k * Nc + n];
    acc += bias[n];
    Cout[idx] = do_relu ? fmaxf(acc, 0.f) : acc;
}

extern "C" void kernel_launch(void* const* d_in, const int* in_sizes, int n_in,
                              void* d_out, int out_size, void* d_ws, size_t ws_size,
                              hipStream_t stream)
{
    const float* x    = (const float*)d_in[0];
    const float* W_ft = (const float*)d_in[1];
    const float* b_ft = (const float*)d_in[2];
    const float* ln_g = (const float*)d_in[3];
    const float* ln_b = (const float*)d_in[4];
    const float* W_g[3] = {(const float*)d_in[5], (const float*)d_in[7], (const float*)d_in[9]};
    const float* b_g[3] = {(const float*)d_in[6], (const float*)d_in[8], (const float*)d_in[10]};
    const float* W_c0 = (const float*)d_in[11];
    const float* b_c0 = (const float*)d_in[12];
    const float* W_c1 = (const float*)d_in[13];
    const float* b_c1 = (const float*)d_in[14];
    const float* W_c2 = (const float*)d_in[15];
    const float* b_c2 = (const float*)d_in[16];
    const int*   edge  = (const int*)d_in[17];
    const int*   batch = (const int*)d_in[18];

    const int N    = in_sizes[18];        // 100000
    const int E    = in_sizes[17] / 2;    // 1600000
    const int Mpad = (N + 127) & ~127;    // 100096
    const int H2   = in_sizes[14];        // 128
    const int Cc   = in_sizes[15] / H2;   // 4
    const int G    = out_size / Cc;       // 512

    const int* srcI = edge;
    const int* dstI = edge + E;

    size_t off = 0;
    auto alloc = [&](size_t bytes) {
        char* p = (char*)d_ws + off;
        off = (off + bytes + 255) & ~(size_t)255;
        return p;
    };
    unsigned short* hh   = (unsigned short*)alloc((size_t)Mpad * 256 * 2);
    unsigned short* hwpb = (unsigned short*)alloc((size_t)Mpad * 256 * 2);
    float* dinv   = (float*)alloc((size_t)Mpad * 4);
    int*   deg    = (int*)alloc((size_t)Mpad * 4);
    int*   rowptr = (int*)alloc((size_t)(N + 1) * 4);
    int*   perm   = (int*)alloc((size_t)E * 4);
    int*   col    = (int*)alloc((size_t)E * 4);
    int*   bsums  = (int*)alloc(1024 * 4);
    int*   starts = (int*)alloc((size_t)(G + 1) * 4);
    float* pooled = (float*)alloc((size_t)G * 256 * 4);
    float* z0     = (float*)alloc((size_t)G * 256 * 4);
    float* z1     = (float*)alloc((size_t)G * H2 * 4);
    unsigned short* Bt[4];
    for (int i = 0; i < 4; ++i)
        Bt[i] = (unsigned short*)alloc((size_t)256 * 512 * 2);
    (void)ws_size; (void)n_in;

    hipMemsetAsync(deg, 0, (size_t)Mpad * 4, stream);
    // zero pad rows of h plane (read by GCN GEMM A staging)
    hipMemsetAsync(hh + (size_t)N * 256, 0, (size_t)(Mpad - N) * 256 * 2, stream);

    // 0. weight prep
    tg_splitB<<<dim3(4, 4, 4), dim3(256), 0, stream>>>(
        W_ft, W_g[0], W_g[1], W_g[2], Bt[0], Bt[1], Bt[2], Bt[3]);

    // 1. fused feature transform + LayerNorm + PE -> single f16 h plane
    tg_ft_ln<<<dim3(Mpad / 128), dim3(256), 0, stream>>>(
        x, Bt[0], b_ft, ln_g, ln_b, hh, N);

    // 2. degrees + CSR build (rows = dst, cols = src)
    tg_count<<<dim3((E + 255) / 256), dim3(256), 0, stream>>>(dstI, deg, perm, E);
    tg_dinv<<<dim3((Mpad + 255) / 256), dim3(256), 0, stream>>>(deg, dinv, Mpad);
    const int NB = (N + 1023) / 1024;
    tg_scan1<<<dim3(NB), dim3(1024), 0, stream>>>(deg, rowptr, bsums, N);
    tg_scan2<<<dim3(1), dim3(1024), 0, stream>>>(bsums, NB);
    tg_scan3<<<dim3((N + 1024) / 1024), dim3(1024), 0, stream>>>(rowptr, bsums, N, E);
    tg_fill<<<dim3((E + 255) / 256), dim3(256), 0, stream>>>(srcI, dstI, rowptr, perm, col, E);

    // 3. GCN layers
    const int nbx = (Mpad / 128) * 2;     // 1-D grid: lg>>1 = row tile, lg&1 = col tile
    for (int l = 0; l < 3; ++l) {
        tg_gemm<<<dim3(nbx), dim3(256), 0, stream>>>(hh, Bt[l + 1], dinv, hwpb);
        tg_aggregate_h<<<dim3((N + 7) / 8), dim3(256), 0, stream>>>(hwpb, rowptr, col, dinv,
                                                                    b_g[l], hh, N);
    }

    // 4. per-graph mean pool
    tg_ranges<<<dim3((G + 256) / 256), dim3(256), 0, stream>>>(batch, starts, N, G);
    tg_pool<<<dim3(G), dim3(256), 0, stream>>>(hh, starts, pooled, G);

    // 5. classifier MLP
    tg_mlp<<<dim3((G * 256 + 255) / 256), dim3(256), 0, stream>>>(pooled, W_c0, b_c0, z0, G, 256, 256, 1);
    tg_mlp<<<dim3((G * H2 + 255) / 256), dim3(256), 0, stream>>>(z0, W_c1, b_c1, z1, G, 256, H2, 1);
    tg_mlp<<<dim3((G * Cc + 255) / 256), dim3(256), 0, stream>>>(z1, W_c2, b_c2, (float*)d_out, G, H2, Cc, 0);
}

// Round 4
// 924.141 us; speedup vs baseline: 1.2825x; 1.1483x over previous
//
#include <hip/hip_runtime.h>
#include <math.h>

// ---------------------------------------------------------------------------
// Temporal GNN. Round 11:
//  * NEW tg_agg_gemm (layers 2,3): fuses aggregate_l + GEMM_{l+1}. Block
//    gathers its 128 rows (same fabric-bound code) straight into a swizzled
//    64KB LDS A-tile, then runs the 128x256 GEMM vs the next weights.
//    Removes the hh write+read at two layer boundaries and overlaps
//    gather-phase blocks with MFMA-phase blocks (512 thr, 80KB LDS,
//    2 blk/CU = 16 waves/CU in gather phase).
//  * tg_ranges folded into tg_pool; 3 MLP launches fused into tg_mlp3.
//  * ft_ln / layer-1 GEMM / final aggregate / CSR build unchanged (r10).
// ---------------------------------------------------------------------------

typedef __attribute__((ext_vector_type(8))) _Float16 half8;  // MFMA A/B frag
typedef __attribute__((ext_vector_type(4))) float floatx4;   // MFMA C/D
typedef __attribute__((ext_vector_type(8))) unsigned short us8; // 16B f16 vec

union HU { _Float16 h; unsigned short u; };

static __device__ __forceinline__ unsigned short f2h(float f) {
    HU x; x.h = (_Float16)f; return x.u;          // v_cvt_f16_f32 (RNE)
}
static __device__ __forceinline__ float h2f(unsigned short s) {
    HU x; x.u = s; return (float)x.h;
}

// async 16B/lane global -> LDS (dest = wave-uniform base + lane*16)
static __device__ __forceinline__ void gl_lds16(const void* g, void* l) {
    __builtin_amdgcn_global_load_lds(
        (const __attribute__((address_space(1))) unsigned int*)(g),
        (__attribute__((address_space(3))) unsigned int*)(l), 16, 0, 0);
}

// sin/cos(ang) for ang up to ~1e5 rad: Cody-Waite 3-term reduction
// + hardware trig on revolutions.
static __device__ __forceinline__ float cw_trig(float ang, bool is_cos) {
    const float i2pi = 0.15915494309189535f;
    const float k = rintf(ang * i2pi);
    float r = fmaf(k, -6.28125f, ang);
    r = fmaf(k, -1.9352436065673828e-3f, r);
    r = fmaf(k, -6.3573019e-8f, r);
    const float rv = r * i2pi;
    return is_cos ? __builtin_amdgcn_cosf(rv) : __builtin_amdgcn_sinf(rv);
}

// Split W[256][256] (k-major) into Bt'[n][512] = [Bh | Bl] f16 (transposed).
__global__ void tg_splitB(const float* __restrict__ W0, const float* __restrict__ W1,
                          const float* __restrict__ W2, const float* __restrict__ W3,
                          unsigned short* __restrict__ B0, unsigned short* __restrict__ B1,
                          unsigned short* __restrict__ B2, unsigned short* __restrict__ B3)
{
    const float* Ws[4] = {W0, W1, W2, W3};
    unsigned short* Bs[4] = {B0, B1, B2, B3};
    const float* W = Ws[blockIdx.z];
    unsigned short* Bt = Bs[blockIdx.z];

    __shared__ float T[64][68];
    const int tk = blockIdx.x * 64, tn = blockIdx.y * 64;
    const int t = threadIdx.x;
#pragma unroll
    for (int j = 0; j < 4; ++j) {
        const int idx = t + 256 * j;
        const int k = idx >> 4, c4 = (idx & 15) * 4;
        const float4 v = *(const float4*)&W[(size_t)(tk + k) * 256 + tn + c4];
        T[k][c4] = v.x; T[k][c4 + 1] = v.y; T[k][c4 + 2] = v.z; T[k][c4 + 3] = v.w;
    }
    __syncthreads();
#pragma unroll
    for (int j = 0; j < 4; ++j) {
        const int idx = t + 256 * j;
        const int n = idx >> 4, q = (idx & 15) * 4;
        unsigned short hh[4], ll[4];
#pragma unroll
        for (int i = 0; i < 4; ++i) {
            const float f = T[q + i][n];
            hh[i] = f2h(f);
            ll[i] = f2h(f - h2f(hh[i]));
        }
        uint2 hp, lp;
        hp.x = (unsigned)hh[0] | ((unsigned)hh[1] << 16);
        hp.y = (unsigned)hh[2] | ((unsigned)hh[3] << 16);
        lp.x = (unsigned)ll[0] | ((unsigned)ll[1] << 16);
        lp.y = (unsigned)ll[2] | ((unsigned)ll[3] << 16);
        unsigned short* row = Bt + (size_t)(tn + n) * 512;
        *(uint2*)&row[tk + q]       = hp;   // Bh
        *(uint2*)&row[256 + tk + q] = lp;   // Bl
    }
}

// ---------------------------------------------------------------------------
// Fused FT GEMM + LayerNorm + PE (round-10 structure, unchanged).
// ---------------------------------------------------------------------------
__global__ __launch_bounds__(256, 2)
void tg_ft_ln(const float* __restrict__ x, const unsigned short* __restrict__ Bt,
              const float* __restrict__ bias, const float* __restrict__ lng,
              const float* __restrict__ lnb, unsigned short* __restrict__ hh, int N)
{
    __shared__ unsigned short sAh[128 * 64];   // 16 KB
    __shared__ unsigned short sAl[128 * 64];   // 16 KB
    __shared__ unsigned short sB[256 * 64];    // 32 KB (Bh then Bl)
    __shared__ float sStats[128][2][2];        // [row][wc][{sum,sumsq}] 2 KB
    __shared__ float sDiv[128];                // PE div table (512 B)

    const int t = threadIdx.x;
    const int w = t >> 6, lane = t & 63;
    const int quad = lane >> 4, l16 = lane & 15;
    const int wr = w >> 1, wc = w & 1;
    const int row0 = blockIdx.x * 128;

    if (t < 128) sDiv[t] = expf((float)(2 * t) * -0.035977892078031970f);

    floatx4 acc[4][8];
#pragma unroll
    for (int i = 0; i < 4; ++i)
#pragma unroll
        for (int j = 0; j < 8; ++j) acc[i][j] = (floatx4){0.f, 0.f, 0.f, 0.f};

    const int arow = t >> 1;
    const int ahalf = t & 1;
    const int srow = lane >> 3;
    const int kgx  = (lane & 7) ^ srow;
    const int rsw  = l16 & 7;

    for (int k4 = 0; k4 < 4; ++k4) {
        const int ka = k4 * 64;
        if (k4) __syncthreads();
        // issue sB = Bh(ka) first (async, overlaps the A chain)
#pragma unroll
        for (int i = 0; i < 8; ++i) {
            const int rr = w * 64 + i * 8;
            gl_lds16(Bt + (size_t)(rr + srow) * 512 + ka + kgx * 8, &sB[rr * 64]);
        }
        // stage A: read f32 x, split to hi/lo f16, swizzled ds_write
        {
            const int grow = row0 + arow;
            const bool ok = grow < N;
            const float* xp = x + (size_t)grow * 256 + ka + ahalf * 32;
#pragma unroll
            for (int j = 0; j < 4; ++j) {
                const int kg = ahalf * 4 + j;
                float4 v0 = {0.f, 0.f, 0.f, 0.f}, v1 = {0.f, 0.f, 0.f, 0.f};
                if (ok) {
                    v0 = *(const float4*)(xp + j * 8);
                    v1 = *(const float4*)(xp + j * 8 + 4);
                }
                const float f[8] = {v0.x, v0.y, v0.z, v0.w, v1.x, v1.y, v1.z, v1.w};
                us8 hi, lo;
#pragma unroll
                for (int i = 0; i < 8; ++i) {
                    hi[i] = f2h(f[i]);
                    lo[i] = f2h(f[i] - h2f(hi[i]));
                }
                const int ad = arow * 64 + ((kg ^ (arow & 7)) << 3);
                *(us8*)&sAh[ad] = hi;
                *(us8*)&sAl[ad] = lo;
            }
        }
        __syncthreads();
        // P0 + P1: Ah.Bh + Al.Bh
#pragma unroll
        for (int ks = 0; ks < 2; ++ks) {
            const int kq = ks * 4 + quad;
            half8 afh[4], afl[4];
#pragma unroll
            for (int rt = 0; rt < 4; ++rt) {
                const int r = wr * 64 + rt * 16 + l16;
                const int off = r * 64 + ((kq ^ rsw) << 3);
                afh[rt] = *(const half8*)&sAh[off];
                afl[rt] = *(const half8*)&sAl[off];
            }
#pragma unroll
            for (int cb = 0; cb < 2; ++cb) {
                half8 bfr[4];
#pragma unroll
                for (int c4 = 0; c4 < 4; ++c4) {
                    const int n = wc * 128 + (cb * 4 + c4) * 16 + l16;
                    bfr[c4] = *(const half8*)&sB[n * 64 + ((kq ^ rsw) << 3)];
                }
#pragma unroll
                for (int c4 = 0; c4 < 4; ++c4)
#pragma unroll
                    for (int rt = 0; rt < 4; ++rt) {
                        acc[rt][cb * 4 + c4] = __builtin_amdgcn_mfma_f32_16x16x32_f16(
                            afh[rt], bfr[c4], acc[rt][cb * 4 + c4], 0, 0, 0);
                        acc[rt][cb * 4 + c4] = __builtin_amdgcn_mfma_f32_16x16x32_f16(
                            afl[rt], bfr[c4], acc[rt][cb * 4 + c4], 0, 0, 0);
                    }
            }
        }
        __syncthreads();
        // stage sB = Bl(ka)
#pragma unroll
        for (int i = 0; i < 8; ++i) {
            const int rr = w * 64 + i * 8;
            gl_lds16(Bt + (size_t)(rr + srow) * 512 + 256 + ka + kgx * 8, &sB[rr * 64]);
        }
        __syncthreads();
        // P2: Ah.Bl
#pragma unroll
        for (int ks = 0; ks < 2; ++ks) {
            const int kq = ks * 4 + quad;
            half8 afh[4];
#pragma unroll
            for (int rt = 0; rt < 4; ++rt) {
                const int r = wr * 64 + rt * 16 + l16;
                afh[rt] = *(const half8*)&sAh[r * 64 + ((kq ^ rsw) << 3)];
            }
#pragma unroll
            for (int cb = 0; cb < 2; ++cb) {
                half8 bfr[4];
#pragma unroll
                for (int c4 = 0; c4 < 4; ++c4) {
                    const int n = wc * 128 + (cb * 4 + c4) * 16 + l16;
                    bfr[c4] = *(const half8*)&sB[n * 64 + ((kq ^ rsw) << 3)];
                }
#pragma unroll
                for (int c4 = 0; c4 < 4; ++c4)
#pragma unroll
                    for (int rt = 0; rt < 4; ++rt)
                        acc[rt][cb * 4 + c4] = __builtin_amdgcn_mfma_f32_16x16x32_f16(
                            afh[rt], bfr[c4], acc[rt][cb * 4 + c4], 0, 0, 0);
            }
        }
    }

    float bs[8], gs[8], bv[8], dv[8];
#pragma unroll
    for (int ct = 0; ct < 8; ++ct) {
        const int gc = wc * 128 + ct * 16 + l16;
        bs[ct] = bias[gc]; gs[ct] = lng[gc]; bv[ct] = lnb[gc];
        dv[ct] = sDiv[gc >> 1];
    }

#pragma unroll
    for (int rt = 0; rt < 4; ++rt) {
#pragma unroll
        for (int i = 0; i < 4; ++i) {
            float s = 0.f, q = 0.f;
#pragma unroll
            for (int ct = 0; ct < 8; ++ct) {
                const float v = fmaxf(acc[rt][ct][i] + bs[ct], 0.f);
                s += v; q += v * v;
            }
#pragma unroll
            for (int m = 1; m < 16; m <<= 1) {
                s += __shfl_xor(s, m, 64);
                q += __shfl_xor(q, m, 64);
            }
            if (l16 == 0) {
                const int rl = wr * 64 + rt * 16 + quad * 4 + i;
                sStats[rl][wc][0] = s;
                sStats[rl][wc][1] = q;
            }
        }
    }
    __syncthreads();

    const bool is_cos = (l16 & 1);
#pragma unroll
    for (int rt = 0; rt < 4; ++rt) {
#pragma unroll
        for (int i = 0; i < 4; ++i) {
            const int rl = wr * 64 + rt * 16 + quad * 4 + i;
            const int gr = row0 + rl;
            if (gr >= N) continue;
            const float sum = sStats[rl][0][0] + sStats[rl][1][0];
            const float sq  = sStats[rl][0][1] + sStats[rl][1][1];
            const float mu  = sum * (1.f / 256.f);
            const float var = sq * (1.f / 256.f) - mu * mu;
            const float rstd = 1.f / sqrtf(var + 1e-5f);
            const float rf = (float)gr;
            unsigned short* orow = hh + (size_t)gr * 256 + wc * 128 + l16;
#pragma unroll
            for (int ct = 0; ct < 8; ++ct) {
                const float v = fmaxf(acc[rt][ct][i] + bs[ct], 0.f);
                const float nrm = (v - mu) * rstd * gs[ct] + bv[ct];
                const float pe = cw_trig(rf * dv[ct], is_cos);
                orow[ct * 16] = f2h(nrm + pe);
            }
        }
    }
}

// Layer-1 GCN GEMM: A-resident chunk order, XCD-paired col tiles.
__global__ __launch_bounds__(256, 3)
void tg_gemm(const unsigned short* __restrict__ Ph,
             const unsigned short* __restrict__ Bt,
             const float* __restrict__ rowscale,
             unsigned short* __restrict__ out)
{
    __shared__ unsigned short sA[128 * 64], sB[128 * 64];  // 16 KB each

    const int t = threadIdx.x;
    const int w = t >> 6, lane = t & 63;
    const int quad = lane >> 4, l16 = lane & 15;
    const int wr = w >> 1, wc = w & 1;

    const int nwg = gridDim.x;
    const int swq = nwg >> 3, swr = nwg & 7;
    const int xcd = blockIdx.x & 7, oidx = blockIdx.x >> 3;
    const int lg = (xcd < swr ? xcd * (swq + 1)
                              : swr * (swq + 1) + (xcd - swr) * swq) + oidx;
    const int row0 = (lg >> 1) * 128;
    const int col0 = (lg & 1) * 128;

    floatx4 acc[4][4];
#pragma unroll
    for (int i = 0; i < 4; ++i)
#pragma unroll
        for (int j = 0; j < 4; ++j) acc[i][j] = (floatx4){0.f, 0.f, 0.f, 0.f};

    const int srow = lane >> 3;
    const int kgx  = (lane & 7) ^ srow;
    const int rsw  = l16 & 7;

    for (int c = 0; c < 8; ++c) {
        const int ka = (c >> 1) << 6;
        const int kb = ((c & 1) << 8) + ka;
        const bool stA = !(c & 1);
        if (c) __syncthreads();
#pragma unroll
        for (int i = 0; i < 4; ++i) {
            const int rr = w * 32 + i * 8;
            if (stA)
                gl_lds16(Ph + (size_t)(row0 + rr + srow) * 256 + ka + kgx * 8, &sA[rr * 64]);
            gl_lds16(Bt + (size_t)(col0 + rr + srow) * 512 + kb + kgx * 8, &sB[rr * 64]);
        }
        __syncthreads();
#pragma unroll
        for (int ks = 0; ks < 2; ++ks) {
            const int kq = ks * 4 + quad;
            half8 af[4], bfr[4];
#pragma unroll
            for (int rt = 0; rt < 4; ++rt) {
                const int r = wr * 64 + rt * 16 + l16;
                af[rt] = *(const half8*)&sA[r * 64 + ((kq ^ rsw) << 3)];
            }
#pragma unroll
            for (int ct = 0; ct < 4; ++ct) {
                const int n = wc * 64 + ct * 16 + l16;
                bfr[ct] = *(const half8*)&sB[n * 64 + ((kq ^ rsw) << 3)];
            }
#pragma unroll
            for (int ct = 0; ct < 4; ++ct)
#pragma unroll
                for (int rt = 0; rt < 4; ++rt)
                    acc[rt][ct] = __builtin_amdgcn_mfma_f32_16x16x32_f16(
                        af[rt], bfr[ct], acc[rt][ct], 0, 0, 0);
        }
    }

#pragma unroll
    for (int rt = 0; rt < 4; ++rt) {
#pragma unroll
        for (int i = 0; i < 4; ++i) {
            const int gr = row0 + wr * 64 + rt * 16 + quad * 4 + i;
            const float s = rowscale[gr];
#pragma unroll
            for (int ct = 0; ct < 4; ++ct) {
                const int gc = col0 + wc * 64 + ct * 16 + l16;
                out[(size_t)gr * 256 + gc] = f2h(acc[rt][ct][i] * s);
            }
        }
    }
}

// ---------------------------------------------------------------------------
// Fused aggregate_l + GEMM_{l+1} (layers 2,3). 512 threads, 80 KB LDS,
// 2 blocks/CU. Phase 1: 16 groups x 32 lanes aggregate 8 rows each
// (relu(dinv*(self+sum)+bias)) -> swizzled f16 hA tile (64 KB).
// Phase 2: hwpOut = f16((hA @ W)*dinv), K'=512, sB staged in 16 pieces.
// ---------------------------------------------------------------------------
__global__ __launch_bounds__(512, 4)
void tg_agg_gemm(const unsigned short* __restrict__ hwpIn,
                 const int* __restrict__ rowptr, const int* __restrict__ col,
                 const float* __restrict__ dinv, const float* __restrict__ bias,
                 const unsigned short* __restrict__ Bt,
                 unsigned short* __restrict__ hwpOut, int N)
{
    __shared__ unsigned short hA[128 * 256];   // 64 KB swizzled h tile
    __shared__ unsigned short sB[128 * 64];    // 16 KB

    const int t = threadIdx.x;
    const int row0 = blockIdx.x * 128;

    // ---- phase 1: aggregate 128 rows ----
    {
        const int g = t >> 5;              // 16 groups of 32 lanes
        const int hl = t & 31;
        const int c = hl * 8;              // 8 f16 = 16 B per lane
        const unsigned short* base = hwpIn + c;
        for (int it = 0; it < 8; ++it) {
            const int lr = g * 8 + it;
            const int row = row0 + lr;
            us8 o = {0, 0, 0, 0, 0, 0, 0, 0};
            if (row < N) {
                const int beg = rowptr[row], end = rowptr[row + 1];
                const us8 sv = *(const us8*)(base + (size_t)row * 256);
                float a[8];
#pragma unroll
                for (int j = 0; j < 8; ++j) a[j] = h2f(sv[j]);
                int p = beg;
                int rem = end - beg;
                int c0[8];
                if (rem >= 8) {
#pragma unroll
                    for (int u = 0; u < 8; ++u) c0[u] = col[p + u];
                }
                while (rem >= 8) {
                    int c1[8];
                    const bool more = rem >= 16;
                    if (more) {
#pragma unroll
                        for (int u = 0; u < 8; ++u) c1[u] = col[p + 8 + u];
                    }
                    us8 v[8];
#pragma unroll
                    for (int u = 0; u < 8; ++u)
                        v[u] = *(const us8*)(base + (size_t)c0[u] * 256);
#pragma unroll
                    for (int u = 0; u < 8; ++u)
#pragma unroll
                        for (int j = 0; j < 8; ++j) a[j] += h2f(v[u][j]);
                    if (more) {
#pragma unroll
                        for (int u = 0; u < 8; ++u) c0[u] = c1[u];
                    }
                    p += 8; rem -= 8;
                }
                if (rem > 0) {
                    const int last = end - 1;
                    int ci[8];
#pragma unroll
                    for (int u = 0; u < 8; ++u) {
                        const int pp = (p + u < last) ? p + u : last;
                        ci[u] = col[pp];
                    }
                    us8 v[8];
#pragma unroll
                    for (int u = 0; u < 8; ++u)
                        v[u] = *(const us8*)(base + (size_t)(u < rem ? ci[u] : row) * 256);
#pragma unroll
                    for (int u = 0; u < 8; ++u) {
                        if (u < rem) {
#pragma unroll
                            for (int j = 0; j < 8; ++j) a[j] += h2f(v[u][j]);
                        }
                    }
                }
                const float di = dinv[row];
                const float4 b0 = *(const float4*)&bias[c];
                const float4 b1 = *(const float4*)&bias[c + 4];
                o[0] = f2h(fmaxf(di * a[0] + b0.x, 0.f));
                o[1] = f2h(fmaxf(di * a[1] + b0.y, 0.f));
                o[2] = f2h(fmaxf(di * a[2] + b0.z, 0.f));
                o[3] = f2h(fmaxf(di * a[3] + b0.w, 0.f));
                o[4] = f2h(fmaxf(di * a[4] + b1.x, 0.f));
                o[5] = f2h(fmaxf(di * a[5] + b1.y, 0.f));
                o[6] = f2h(fmaxf(di * a[6] + b1.z, 0.f));
                o[7] = f2h(fmaxf(di * a[7] + b1.w, 0.f));
            }
            // swizzled store: k-group (hl&7) of chunk (c&~63) -> slot ^(lr&7)
            const int ad = lr * 256 + (c & ~63) + (((hl & 7) ^ (lr & 7)) << 3);
            *(us8*)&hA[ad] = o;
        }
    }
    __syncthreads();

    // ---- phase 2: GEMM hA @ Bt -> hwpOut ----
    const int w = t >> 6, lane = t & 63;
    const int quad = lane >> 4, l16 = lane & 15;
    const int rb = (w & 1) * 64;           // wave row block
    const int cq = (w >> 1) * 32;          // col sub-strip within 128-half
    const int srow = lane >> 3;
    const int kgx  = (lane & 7) ^ srow;
    const int rsw  = l16 & 7;

    floatx4 acc[4][4];
#pragma unroll
    for (int i = 0; i < 4; ++i)
#pragma unroll
        for (int j = 0; j < 4; ++j) acc[i][j] = (floatx4){0.f, 0.f, 0.f, 0.f};

    for (int c8 = 0; c8 < 8; ++c8) {
        const int ka = (c8 >> 1) << 6;
        const int kb = ((c8 & 1) << 8) + ka;
#pragma unroll
        for (int h = 0; h < 2; ++h) {
            if (c8 || h) __syncthreads();     // prior MFMA done reading sB
            {   // stage B' rows h*128 + w*16 .. +15
                const int rr = w * 16;
                gl_lds16(Bt + (size_t)(h * 128 + rr + srow) * 512 + kb + kgx * 8,
                         &sB[rr * 64]);
                gl_lds16(Bt + (size_t)(h * 128 + rr + 8 + srow) * 512 + kb + kgx * 8,
                         &sB[(rr + 8) * 64]);
            }
            __syncthreads();
#pragma unroll
            for (int ks = 0; ks < 2; ++ks) {
                const int kq = ks * 4 + quad;
                half8 af[4], bf[2];
#pragma unroll
                for (int rt = 0; rt < 4; ++rt) {
                    const int r = rb + rt * 16 + l16;
                    af[rt] = *(const half8*)&hA[r * 256 + ka + ((kq ^ rsw) << 3)];
                }
#pragma unroll
                for (int ct = 0; ct < 2; ++ct) {
                    const int br = cq + ct * 16 + l16;
                    bf[ct] = *(const half8*)&sB[br * 64 + ((kq ^ rsw) << 3)];
                }
#pragma unroll
                for (int ct = 0; ct < 2; ++ct)
#pragma unroll
                    for (int rt = 0; rt < 4; ++rt)
                        acc[rt][h * 2 + ct] = __builtin_amdgcn_mfma_f32_16x16x32_f16(
                            af[rt], bf[ct], acc[rt][h * 2 + ct], 0, 0, 0);
            }
        }
    }

#pragma unroll
    for (int rt = 0; rt < 4; ++rt) {
#pragma unroll
        for (int i = 0; i < 4; ++i) {
            const int gr = row0 + rb + rt * 16 + quad * 4 + i;
            const float s = dinv[gr];
#pragma unroll
            for (int j = 0; j < 4; ++j) {
                const int gc = (j >> 1) * 128 + cq + (j & 1) * 16 + l16;
                hwpOut[(size_t)gr * 256 + gc] = f2h(acc[rt][j][i] * s);
            }
        }
    }
}

// count pass also records each edge's slot within its dst row (perm).
__global__ void tg_count(const int* __restrict__ dst, int* __restrict__ deg,
                         int* __restrict__ perm, int E)
{
    const int e = blockIdx.x * blockDim.x + threadIdx.x;
    if (e < E) perm[e] = atomicAdd(&deg[dst[e]], 1);
}

__global__ void tg_dinv(const int* __restrict__ deg, float* __restrict__ dinv, int N)
{
    const int i = blockIdx.x * blockDim.x + threadIdx.x;
    if (i < N) dinv[i] = 1.f / sqrtf((float)(deg[i] + 1));  // +1 self-loop
}

__global__ void tg_scan1(const int* __restrict__ cnt, int* __restrict__ out,
                         int* __restrict__ sums, int N)
{
    __shared__ int tmp[1024];
    const int t = threadIdx.x;
    const int gid = blockIdx.x * 1024 + t;
    const int v = (gid < N) ? cnt[gid] : 0;
    tmp[t] = v;
    __syncthreads();
    for (int o = 1; o < 1024; o <<= 1) {
        const int add = (t >= o) ? tmp[t - o] : 0;
        __syncthreads();
        tmp[t] += add;
        __syncthreads();
    }
    if (gid < N) out[gid] = tmp[t] - v;
    if (t == 1023) sums[blockIdx.x] = tmp[t];
}

__global__ void tg_scan2(int* __restrict__ sums, int nb)
{
    __shared__ int tmp[1024];
    const int t = threadIdx.x;
    const int v = (t < nb) ? sums[t] : 0;
    tmp[t] = v;
    __syncthreads();
    for (int o = 1; o < 1024; o <<= 1) {
        const int add = (t >= o) ? tmp[t - o] : 0;
        __syncthreads();
        tmp[t] += add;
        __syncthreads();
    }
    if (t < nb) sums[t] = tmp[t] - v;
}

__global__ void tg_scan3(int* __restrict__ rowptr, const int* __restrict__ offs,
                         int N, int E)
{
    const int gid = blockIdx.x * 1024 + threadIdx.x;
    if (gid < N) rowptr[gid] += offs[gid >> 10];
    else if (gid == N) rowptr[N] = E;
}

// atomic-free fill using perm from the count pass
__global__ void tg_fill(const int* __restrict__ src, const int* __restrict__ dst,
                        const int* __restrict__ rowptr, const int* __restrict__ perm,
                        int* __restrict__ col, int E)
{
    const int e = blockIdx.x * blockDim.x + threadIdx.x;
    if (e >= E) return;
    col[rowptr[dst[e]] + perm[e]] = src[e];
}

// Final standalone aggregate (layer 3 -> hh, consumed by pool).
__global__ void tg_aggregate_h(const unsigned short* __restrict__ hwpb,
                               const int* __restrict__ rowptr, const int* __restrict__ col,
                               const float* __restrict__ dinv, const float* __restrict__ bias,
                               unsigned short* __restrict__ hh, int N)
{
    const int gt = blockIdx.x * blockDim.x + threadIdx.x;
    const int row = gt >> 5;               // 32-thread group per row
    if (row >= N) return;
    const int hl = gt & 31;
    const int c = hl * 8;                  // 8 halves = 16 B per lane

    const unsigned short* base = hwpb + c;
    const int beg = rowptr[row], end = rowptr[row + 1];

    const us8 sv = *(const us8*)(base + (size_t)row * 256);
    float a[8];
#pragma unroll
    for (int j = 0; j < 8; ++j) a[j] = h2f(sv[j]);

    int p = beg;
    int rem = end - beg;
    int c0[8];
    if (rem >= 8) {
#pragma unroll
        for (int u = 0; u < 8; ++u) c0[u] = col[p + u];
    }
    while (rem >= 8) {
        int c1[8];
        const bool more = rem >= 16;
        if (more) {
#pragma unroll
            for (int u = 0; u < 8; ++u) c1[u] = col[p + 8 + u];
        }
        us8 v[8];
#pragma unroll
        for (int u = 0; u < 8; ++u)
            v[u] = *(const us8*)(base + (size_t)c0[u] * 256);
#pragma unroll
        for (int u = 0; u < 8; ++u)
#pragma unroll
            for (int j = 0; j < 8; ++j) a[j] += h2f(v[u][j]);
        if (more) {
#pragma unroll
            for (int u = 0; u < 8; ++u) c0[u] = c1[u];
        }
        p += 8; rem -= 8;
    }
    if (rem > 0) {
        const int last = end - 1;
        int ci[8];
#pragma unroll
        for (int u = 0; u < 8; ++u) {
            const int pp = (p + u < last) ? p + u : last;   // clamp: no OOB
            ci[u] = col[pp];
        }
        us8 v[8];
#pragma unroll
        for (int u = 0; u < 8; ++u)
            v[u] = *(const us8*)(base + (size_t)(u < rem ? ci[u] : row) * 256);
#pragma unroll
        for (int u = 0; u < 8; ++u) {
            if (u < rem) {
#pragma unroll
                for (int j = 0; j < 8; ++j) a[j] += h2f(v[u][j]);
            }
        }
    }

    const float di = dinv[row];
    const float4 b0 = *(const float4*)&bias[c];
    const float4 b1 = *(const float4*)&bias[c + 4];
    us8 o;
    o[0] = f2h(fmaxf(di * a[0] + b0.x, 0.f));
    o[1] = f2h(fmaxf(di * a[1] + b0.y, 0.f));
    o[2] = f2h(fmaxf(di * a[2] + b0.z, 0.f));
    o[3] = f2h(fmaxf(di * a[3] + b0.w, 0.f));
    o[4] = f2h(fmaxf(di * a[4] + b1.x, 0.f));
    o[5] = f2h(fmaxf(di * a[5] + b1.y, 0.f));
    o[6] = f2h(fmaxf(di * a[6] + b1.z, 0.f));
    o[7] = f2h(fmaxf(di * a[7] + b1.w, 0.f));
    *(us8*)&hh[(size_t)row * 256 + c] = o;
}

// Mean-pool: block per graph (ranges inlined via binary search on batch).
__global__ void tg_pool(const unsigned short* __restrict__ hh,
                        const int* __restrict__ batch, float* __restrict__ pooled,
                        int N, int G)
{
    __shared__ float sh[4][64][4];
    __shared__ int sBE[2];
    const int g = blockIdx.x;
    const int t = threadIdx.x;
    if (t < 2) {
        const int target = g + t;
        int lo = 0, hi = N;
        while (lo < hi) {
            const int mid = (lo + hi) >> 1;
            if (batch[mid] < target) lo = mid + 1; else hi = mid;
        }
        sBE[t] = lo;
    }
    __syncthreads();
    const int beg = sBE[0], end = sBE[1];
    const int wv = t >> 6, lane = t & 63;
    const int c = lane * 4;
    float s0 = 0.f, s1 = 0.f, s2 = 0.f, s3 = 0.f;
    for (int r = beg + wv; r < end; r += 4) {
        const ushort4 vh = *(const ushort4*)&hh[(size_t)r * 256 + c];
        s0 += h2f(vh.x); s1 += h2f(vh.y); s2 += h2f(vh.z); s3 += h2f(vh.w);
    }
    sh[wv][lane][0] = s0; sh[wv][lane][1] = s1;
    sh[wv][lane][2] = s2; sh[wv][lane][3] = s3;
    __syncthreads();
    if (t < 64) {
        const float inv = 1.f / fmaxf((float)(end - beg), 1.f);
        float4 o;
        o.x = (sh[0][t][0] + sh[1][t][0] + sh[2][t][0] + sh[3][t][0]) * inv;
        o.y = (sh[0][t][1] + sh[1][t][1] + sh[2][t][1] + sh[3][t][1]) * inv;
        o.z = (sh[0][t][2] + sh[1][t][2] + sh[2][t][2] + sh[3][t][2]) * inv;
        o.w = (sh[0][t][3] + sh[1][t][3] + sh[2][t][3] + sh[3][t][3]) * inv;
        *(float4*)&pooled[(size_t)g * 256 + t * 4] = o;
    }
}

// Fused 3-layer classifier MLP: one block per graph.
__global__ __launch_bounds__(256)
void tg_mlp3(const float* __restrict__ pooled,
             const float* __restrict__ W0, const float* __restrict__ b0,
             const float* __restrict__ W1, const float* __restrict__ b1,
             const float* __restrict__ W2, const float* __restrict__ b2,
             float* __restrict__ out, int H2, int Cc)
{
    __shared__ float zin[256];
    __shared__ float z0[256];
    __shared__ float z1[256];
    const int g = blockIdx.x;
    const int t = threadIdx.x;
    zin[t] = pooled[(size_t)g * 256 + t];
    __syncthreads();
    float a = 0.f;
    for (int k = 0; k < 256; ++k) a += zin[k] * W0[(size_t)k * 256 + t];
    z0[t] = fmaxf(a + b0[t], 0.f);
    __syncthreads();
    if (t < H2) {
        float a1 = 0.f;
        for (int k = 0; k < 256; ++k) a1 += z0[k] * W1[(size_t)k * H2 + t];
        z1[t] = fmaxf(a1 + b1[t], 0.f);
    }
    __syncthreads();
    if (t < Cc) {
        float a2 = 0.f;
        for (int k = 0; k < H2; ++k) a2 += z1[k] * W2[(size_t)k * Cc + t];
        out[(size_t)g * Cc + t] = a2 + b2[t];
    }
}

extern "C" void kernel_launch(void* const* d_in, const int* in_sizes, int n_in,
                              void* d_out, int out_size, void* d_ws, size_t ws_size,
                              hipStream_t stream)
{
    const float* x    = (const float*)d_in[0];
    const float* W_ft = (const float*)d_in[1];
    const float* b_ft = (const float*)d_in[2];
    const float* ln_g = (const float*)d_in[3];
    const float* ln_b = (const float*)d_in[4];
    const float* W_g[3] = {(const float*)d_in[5], (const float*)d_in[7], (const float*)d_in[9]};
    const float* b_g[3] = {(const float*)d_in[6], (const float*)d_in[8], (const float*)d_in[10]};
    const float* W_c0 = (const float*)d_in[11];
    const float* b_c0 = (const float*)d_in[12];
    const float* W_c1 = (const float*)d_in[13];
    const float* b_c1 = (const float*)d_in[14];
    const float* W_c2 = (const float*)d_in[15];
    const float* b_c2 = (const float*)d_in[16];
    const int*   edge  = (const int*)d_in[17];
    const int*   batch = (const int*)d_in[18];

    const int N    = in_sizes[18];        // 100000
    const int E    = in_sizes[17] / 2;    // 1600000
    const int Mpad = (N + 127) & ~127;    // 100096
    const int H2   = in_sizes[14];        // 128
    const int Cc   = in_sizes[15] / H2;   // 4
    const int G    = out_size / Cc;       // 512

    const int* srcI = edge;
    const int* dstI = edge + E;

    size_t off = 0;
    auto alloc = [&](size_t bytes) {
        char* p = (char*)d_ws + off;
        off = (off + bytes + 255) & ~(size_t)255;
        return p;
    };
    unsigned short* hh    = (unsigned short*)alloc((size_t)Mpad * 256 * 2);
    unsigned short* hwpbA = (unsigned short*)alloc((size_t)Mpad * 256 * 2);
    unsigned short* hwpbB = (unsigned short*)alloc((size_t)Mpad * 256 * 2);
    float* dinv   = (float*)alloc((size_t)Mpad * 4);
    int*   deg    = (int*)alloc((size_t)Mpad * 4);
    int*   rowptr = (int*)alloc((size_t)(N + 1) * 4);
    int*   perm   = (int*)alloc((size_t)E * 4);
    int*   col    = (int*)alloc((size_t)E * 4);
    int*   bsums  = (int*)alloc(1024 * 4);
    float* pooled = (float*)alloc((size_t)G * 256 * 4);
    unsigned short* Bt[4];
    for (int i = 0; i < 4; ++i)
        Bt[i] = (unsigned short*)alloc((size_t)256 * 512 * 2);
    (void)ws_size; (void)n_in;

    hipMemsetAsync(deg, 0, (size_t)Mpad * 4, stream);
    // zero pad rows of h plane (read by layer-1 GEMM A staging)
    hipMemsetAsync(hh + (size_t)N * 256, 0, (size_t)(Mpad - N) * 256 * 2, stream);

    // 0. weight prep
    tg_splitB<<<dim3(4, 4, 4), dim3(256), 0, stream>>>(
        W_ft, W_g[0], W_g[1], W_g[2], Bt[0], Bt[1], Bt[2], Bt[3]);

    // 1. fused feature transform + LayerNorm + PE -> single f16 h plane
    tg_ft_ln<<<dim3(Mpad / 128), dim3(256), 0, stream>>>(
        x, Bt[0], b_ft, ln_g, ln_b, hh, N);

    // 2. degrees + CSR build (rows = dst, cols = src)
    tg_count<<<dim3((E + 255) / 256), dim3(256), 0, stream>>>(dstI, deg, perm, E);
    tg_dinv<<<dim3((Mpad + 255) / 256), dim3(256), 0, stream>>>(deg, dinv, Mpad);
    const int NB = (N + 1023) / 1024;
    tg_scan1<<<dim3(NB), dim3(1024), 0, stream>>>(deg, rowptr, bsums, N);
    tg_scan2<<<dim3(1), dim3(1024), 0, stream>>>(bsums, NB);
    tg_scan3<<<dim3((N + 1024) / 1024), dim3(1024), 0, stream>>>(rowptr, bsums, N, E);
    tg_fill<<<dim3((E + 255) / 256), dim3(256), 0, stream>>>(srcI, dstI, rowptr, perm, col, E);

    // 3. GCN layers: gemm1 standalone; layers 2,3 fused (agg_l + gemm_{l+1});
    //    final aggregate standalone -> hh
    const int nbx = (Mpad / 128) * 2;
    tg_gemm<<<dim3(nbx), dim3(256), 0, stream>>>(hh, Bt[1], dinv, hwpbA);
    const int nfb = Mpad / 128;
    tg_agg_gemm<<<dim3(nfb), dim3(512), 0, stream>>>(hwpbA, rowptr, col, dinv,
                                                     b_g[0], Bt[2], hwpbB, N);
    tg_agg_gemm<<<dim3(nfb), dim3(512), 0, stream>>>(hwpbB, rowptr, col, dinv,
                                                     b_g[1], Bt[3], hwpbA, N);
    tg_aggregate_h<<<dim3((N + 7) / 8), dim3(256), 0, stream>>>(hwpbA, rowptr, col, dinv,
                                                                b_g[2], hh, N);

    // 4. per-graph mean pool (ranges inlined)
    tg_pool<<<dim3(G), dim3(256), 0, stream>>>(hh, batch, pooled, N, G);

    // 5. fused classifier MLP
    tg_mlp3<<<dim3(G), dim3(256), 0, stream>>>(pooled, W_c0, b_c0, W_c1, b_c1,
                                               W_c2, b_c2, (float*)d_out, H2, Cc);
}